// Round 1
// 1839.450 us; speedup vs baseline: 1.0067x; 1.0067x over previous
//
#include <hip/hip_runtime.h>
#include <stdint.h>
#include <stddef.h>

#define B_ 4
#define C_ 256
#define T_ 128
#define NB_ 64
#define NF_ 512
#define PLAT_ (T_*NB_)    // 8192
#define PSIDE_ (T_*NF_)   // 65536

using bf16x8 = __attribute__((ext_vector_type(8))) short;
using bf16x4 = __attribute__((ext_vector_type(4))) short;
using f32x4  = __attribute__((ext_vector_type(4))) float;

__device__ __forceinline__ float b2f(unsigned short h) {
  unsigned int u = ((unsigned int)h) << 16;
  return __builtin_bit_cast(float, u);
}
__device__ __forceinline__ unsigned short f2b(float f) {
  unsigned int u = __builtin_bit_cast(unsigned int, f);
  u += 0x7FFFu + ((u >> 16) & 1u);
  return (unsigned short)(u >> 16);
}

__device__ __forceinline__ bf16x8 ld8(const unsigned short* p) {
  return *(const bf16x8*)p;
}
__device__ __forceinline__ bf16x8 ld8(const float* p) {
  float4 a = *(const float4*)p;
  float4 b = *(const float4*)(p + 4);
  bf16x8 r;
  r[0] = (short)f2b(a.x); r[1] = (short)f2b(a.y);
  r[2] = (short)f2b(a.z); r[3] = (short)f2b(a.w);
  r[4] = (short)f2b(b.x); r[5] = (short)f2b(b.y);
  r[6] = (short)f2b(b.z); r[7] = (short)f2b(b.w);
  return r;
}
__device__ __forceinline__ float ldv(float v) { return v; }
__device__ __forceinline__ float ldv(unsigned short v) { return b2f(v); }
__device__ __forceinline__ void stv(float* p, float v) { *p = v; }
__device__ __forceinline__ void stv(unsigned short* p, float v) { *p = f2b(v); }

// async global->LDS, 16B per lane; lds dst must be wave-uniform base (lane*16 added by HW)
__device__ __forceinline__ void gload16(const void* g, void* l) {
  __builtin_amdgcn_global_load_lds(
      (const __attribute__((address_space(1))) void*)g,
      (__attribute__((address_space(3))) void*)l, 16, 0, 0);
}

enum { EPI_NONE = 0, EPI_SILU = 1, EPI_SKIP = 2, EPI_RESID = 3, EPI_SWIGLU = 4 };

// fold per-channel norm weight into conv weight (fp32 in, bf16 out)
__global__ __launch_bounds__(256) void wprep_k(const float* __restrict__ w,
                                               const float* __restrict__ nw,
                                               unsigned short* __restrict__ out, int n)
{
  int i = blockIdx.x * 256 + threadIdx.x;
  if (i < n) out[i] = f2b(w[i] * nw[i & 255]);
}

// plain fp32 -> bf16 convert
__global__ __launch_bounds__(256) void cvt_k(const float* __restrict__ in,
                                             unsigned short* __restrict__ out, int n)
{
  int i = blockIdx.x * 256 + threadIdx.x;
  if (i < n) out[i] = f2b(in[i]);
}

// weight fold: out[m][c] = bf16( sum_j A[m][j] * Bm[j][c] )  (q_w @ qmlp_out)
__global__ __launch_bounds__(256) void foldw_k(const float* __restrict__ A,
                                               const float* __restrict__ Bm,
                                               unsigned short* __restrict__ out)
{
  const int m = blockIdx.x;
  const int c = threadIdx.x;
  float acc = 0.f;
  #pragma unroll 8
  for (int j = 0; j < C_; ++j) acc = fmaf(A[m * C_ + j], Bm[j * C_ + c], acc);
  out[m * C_ + c] = f2b(acc);
}

// bias fold: bout[m] = sum_j A[m][j]*bin[j] + badd[m]
__global__ __launch_bounds__(256) void foldb_k(const float* __restrict__ A,
                                               const float* __restrict__ bin,
                                               const float* __restrict__ badd,
                                               float* __restrict__ bout)
{
  const int m = threadIdx.x;
  float acc = 0.f;
  #pragma unroll 8
  for (int j = 0; j < C_; ++j) acc = fmaf(A[m * C_ + j], bin[j], acc);
  bout[m] = acc + badd[m];
}

// -------------------------------------------------------------------------
// GEMM over channels. Two X layouts:
//  XT=true : X is bf16 transposed [z][pix][C_] (row = pixel, k contiguous) -> global_load_lds
//  XT=false: X is fp32 [z][C_][Xs] (k = row) -> convert+scatter transpose; RMS may be fused
// Y layouts: YT=true -> bf16 transposed [z][pix][C_]; YT=false -> [z][C_][Ys] (fp32 or bf16)
// BM=64, BN=128, BK=32, 4 waves. LDS sX linear [128][32] with chunk-XOR swizzle:
//   slot s of row n holds global k-chunk s ^ u(n), u(n) = (n&3)^((n>>2)&3)  (2-way banks)
template<int EPI, bool RMS, bool XT, typename TY, bool YT>
__global__ __launch_bounds__(256) void gemm_k(
    const void* __restrict__ Xv,
    const unsigned short* __restrict__ W,
    const float* __restrict__ bias,
    const float* __restrict__ sscale,
    TY* Y,
    int Xs, int Xoff, int Ys, int Yoff)
{
  constexpr bool DUAL = (EPI == EPI_SWIGLU);
  __shared__ unsigned short sA[DUAL ? 2 : 1][64 * 40];
  __shared__ unsigned short sX[128 * 32];

  const int tid = threadIdx.x;
  const int lane = tid & 63;
  const int wid = tid >> 6;
  const int l15 = lane & 15;
  const int q4 = lane >> 4;
  const int z = blockIdx.z;
  const int p0 = blockIdx.x * 128;
  const int m0 = blockIdx.y * 64;
  const int mh = wid >> 1, nh = wid & 1;

  const float* Xf = nullptr;
  const unsigned short* Xt = nullptr;
  if constexpr (XT) Xt = (const unsigned short*)Xv + ((size_t)z * Xs + Xoff + p0) * C_;
  else              Xf = (const float*)Xv + (size_t)z * C_ * Xs + Xoff + p0;

  const f32x4 zf = {0.f, 0.f, 0.f, 0.f};
  f32x4 acc0[2][4];
  f32x4 acc1[DUAL ? 2 : 1][4];
  #pragma unroll
  for (int i = 0; i < 2; ++i)
    #pragma unroll
    for (int j = 0; j < 4; ++j) { acc0[i][j] = zf; if constexpr (DUAL) acc1[i][j] = zf; }

  // W staging map
  const int arow = tid >> 2;
  const int acol = (tid & 3) << 3;
  // fp32 path map
  const int xr = tid >> 4;          // 0..15 (row within 16-row pass)
  const int xc = (tid & 15) << 3;   // col base (8 cols per thread)
  // fast path lane constants
  const int usw = ((lane >> 2) & 3) ^ ((lane >> 4) & 3);
  const int un  = (l15 & 3) ^ ((l15 >> 2) & 3);

  float sq[8];
  int bju[8];
  if constexpr (!XT) {
    #pragma unroll
    for (int j = 0; j < 8; ++j) {
      int n = xc + j;
      int uj = (n & 3) ^ ((n >> 2) & 3);
      bju[j] = (n * 64 + (xr & 7) * 2) ^ (uj << 4);   // byte addr sans chunk bits
      sq[j] = 0.f;
    }
  }

  for (int kt = 0; kt < 8; ++kt) {
    if constexpr (XT) {
      // 128 rows x 64B; wave stages rows [wid*32, wid*32+32)
      #pragma unroll
      for (int j2 = 0; j2 < 2; ++j2) {
        int rbase = wid * 32 + j2 * 16;
        const unsigned short* src = Xt + (size_t)(rbase + (lane >> 2)) * C_
                                    + kt * 32 + (((lane & 3) ^ usw) << 3);
        gload16(src, &sX[rbase * 32]);
      }
    } else {
      char* sxb = (char*)sX;
      #pragma unroll
      for (int pass = 0; pass < 2; ++pass) {
        int r = xr + pass * 16;
        const float* srcp = Xf + (size_t)(kt * 32 + r) * Xs + xc;
        float4 a = *(const float4*)srcp;
        float4 b = *(const float4*)(srcp + 4);
        float v[8] = {a.x, a.y, a.z, a.w, b.x, b.y, b.z, b.w};
        int g16 = (r >> 3) << 4;
        #pragma unroll
        for (int j = 0; j < 8; ++j) {
          if constexpr (RMS) sq[j] = fmaf(v[j], v[j], sq[j]);
          *(unsigned short*)(sxb + (bju[j] ^ g16)) = f2b(v[j]);
        }
      }
    }
    // stage weights 64x32
    {
      bf16x8 a8 = ld8(W + (size_t)(m0 + arow) * C_ + kt * 32 + acol);
      *(bf16x8*)(&sA[0][arow * 40 + acol]) = a8;
      if constexpr (DUAL) {
        bf16x8 a8b = ld8(W + (size_t)(C_ + m0 + arow) * C_ + kt * 32 + acol);
        *(bf16x8*)(&sA[1][arow * 40 + acol]) = a8b;
      }
    }
    __syncthreads();

    bf16x8 af0[2], af1[2], bfr[4];
    #pragma unroll
    for (int mf = 0; mf < 2; ++mf) {
      int row = mh * 32 + mf * 16 + l15;
      af0[mf] = *(const bf16x8*)(&sA[0][row * 40 + q4 * 8]);
      if constexpr (DUAL) af1[mf] = *(const bf16x8*)(&sA[1][row * 40 + q4 * 8]);
    }
    #pragma unroll
    for (int nf = 0; nf < 4; ++nf) {
      int n = nh * 64 + nf * 16 + l15;
      bfr[nf] = *(const bf16x8*)(&sX[n * 32 + ((q4 ^ un) << 3)]);
    }
    #pragma unroll
    for (int mf = 0; mf < 2; ++mf)
      #pragma unroll
      for (int nf = 0; nf < 4; ++nf) {
        acc0[mf][nf] = __builtin_amdgcn_mfma_f32_16x16x32_bf16(af0[mf], bfr[nf], acc0[mf][nf], 0, 0, 0);
        if constexpr (DUAL)
          acc1[mf][nf] = __builtin_amdgcn_mfma_f32_16x16x32_bf16(af1[mf], bfr[nf], acc1[mf][nf], 0, 0, 0);
      }
    __syncthreads();
  }

  // fused RMS colscale
  float cs[4] = {1.f, 1.f, 1.f, 1.f};
  if constexpr (RMS) {
    __shared__ float red[4][128];
    #pragma unroll
    for (int j = 0; j < 8; ++j) {
      sq[j] += __shfl_xor(sq[j], 16);
      sq[j] += __shfl_xor(sq[j], 32);
    }
    if (lane < 16) {
      #pragma unroll
      for (int j = 0; j < 8; ++j) red[wid][lane * 8 + j] = sq[j];
    }
    __syncthreads();
    #pragma unroll
    for (int nf = 0; nf < 4; ++nf) {
      int n = nh * 64 + nf * 16 + l15;
      cs[nf] = rsqrtf((red[0][n] + red[1][n] + red[2][n] + red[3][n]) * (1.0f / (float)C_) + 1e-6f);
    }
  }

  // epilogue
  float qss = 0.f;
  if constexpr (EPI == EPI_SKIP) qss = sscale[0];
  TY* Yb = nullptr;
  if constexpr (!YT) Yb = Y + (size_t)z * C_ * Ys + Yoff;

  #pragma unroll
  for (int mf = 0; mf < 2; ++mf) {
    const int mb = m0 + mh * 32 + mf * 16 + q4 * 4;
    const float4 b1 = *(const float4*)(bias + mb);
    float4 b2 = {0.f, 0.f, 0.f, 0.f};
    if constexpr (DUAL) b2 = *(const float4*)(bias + C_ + mb);
    #pragma unroll
    for (int nf = 0; nf < 4; ++nf) {
      const int pl = p0 + nh * 64 + nf * 16 + l15;
      if constexpr (YT) {
        bf16x4 pk;
        #pragma unroll
        for (int r = 0; r < 4; ++r) {
          float y = acc0[mf][nf][r] * cs[nf] + ((const float*)&b1)[r];
          if constexpr (EPI == EPI_SILU) y = y / (1.0f + __expf(-y));
          if constexpr (EPI == EPI_SWIGLU) {
            float g = acc1[mf][nf][r] * cs[nf] + ((const float*)&b2)[r];
            y = y * (g / (1.0f + __expf(-g)));
          }
          pk[r] = (short)f2b(y);
        }
        *(bf16x4*)(Y + ((size_t)z * Ys + Yoff + pl) * C_ + mb) = pk;
      } else {
        #pragma unroll
        for (int r = 0; r < 4; ++r) {
          size_t oidx = (size_t)(mb + r) * Ys + pl;
          float y = acc0[mf][nf][r] * cs[nf] + ((const float*)&b1)[r];
          if constexpr (EPI == EPI_SILU) y = y / (1.0f + __expf(-y));
          if constexpr (EPI == EPI_SWIGLU) {
            float g = acc1[mf][nf][r] * cs[nf] + ((const float*)&b2)[r];
            y = y * (g / (1.0f + __expf(-g)));
          }
          if constexpr (EPI == EPI_SKIP) y += qss * ldv(Yb[oidx]);
          if constexpr (EPI == EPI_RESID) y += ldv(Yb[oidx]);
          stv(&Yb[oidx], y);
        }
      }
    }
  }
}

// -------------------------------------------------------------------------
// Fused cross-attention, one block per (z, t_local).
// Q, K transposed bf16 [pix][C_]; V non-transposed [C_][pix]; O transposed (in-place on Q buf).
// sK/sQ: linear [64][256] with 8-way chunk XOR: slot s of row n holds chunk s ^ (n&7).
__global__ __launch_bounds__(256) void attn_k(
    const unsigned short* Q,
    const unsigned short* __restrict__ Kp,
    const unsigned short* __restrict__ Vp,
    const float* __restrict__ basis,
    const float* __restrict__ ssp,
    const float* __restrict__ psp,
    unsigned short* O,
    int PsQ, int t0, int ltc)
{
  __shared__ unsigned short sK[64 * 256];
  __shared__ unsigned short sQ[64 * 256];
  __shared__ unsigned short sV[256 * 72];   // [c][n] (A-operand)
  __shared__ unsigned short sW[64 * 72];    // [f][n] softmax weights (B-operand)
  __shared__ unsigned short sB[64 * 72];    // [n][f] bias chunk

  const int tid = threadIdx.x;
  const int lane = tid & 63;
  const int wid = tid >> 6;
  const int l15 = lane & 15;
  const int q4 = lane >> 4;
  const int z = blockIdx.x >> ltc;
  const int tl = blockIdx.x & ((1 << ltc) - 1);

  const unsigned short* Qt = Q + ((size_t)z * PsQ + (size_t)tl * NF_) * C_;
  unsigned short*       Ot = O + ((size_t)z * PsQ + (size_t)tl * NF_) * C_;
  const unsigned short* Kt = Kp + ((size_t)z * PLAT_ + (size_t)(t0 + tl) * NB_) * C_;
  const size_t vbase = (size_t)z * C_ * PLAT_ + (size_t)(t0 + tl) * NB_;

  const float ss = ssp[0];
  const float ps = psp[0];
  const f32x4 zf = {0.f, 0.f, 0.f, 0.f};

  // stage K (gload_lds, swizzled) and V (reg path) once per block
  {
    #pragma unroll
    for (int it = 0; it < 8; ++it) {
      int i = wid * 8 + it;
      int n = 2 * i + (lane >> 5);
      int sc = (lane & 31) ^ (n & 7);
      gload16(Kt + (size_t)n * C_ + (sc << 3), &sK[i * 512]);
    }
    const int c0 = tid >> 3;
    const int n0 = (tid & 7) << 3;
    #pragma unroll
    for (int pass = 0; pass < 8; ++pass) {
      int c = c0 + pass * 32;
      bf16x8 v8 = *(const bf16x8*)(Vp + vbase + (size_t)c * PLAT_ + n0);
      *(bf16x8*)(&sV[c * 72 + n0]) = v8;
    }
  }

  for (int fc = 0; fc < 8; ++fc) {
    const int f0 = fc * 64;
    // stage Q chunk (gload_lds, swizzled) and fp32 bias chunk [n][f]
    #pragma unroll
    for (int it = 0; it < 8; ++it) {
      int i = wid * 8 + it;
      int n = 2 * i + (lane >> 5);
      int sc = (lane & 31) ^ (n & 7);
      gload16(Qt + (size_t)(f0 + n) * C_ + (sc << 3), &sQ[i * 512]);
    }
    {
      const int nr = tid >> 3;
      const int fl0 = (tid & 7) << 3;
      #pragma unroll
      for (int pass = 0; pass < 2; ++pass) {
        int nn = nr + pass * 32;
        bf16x8 b8 = ld8(basis + (size_t)nn * NF_ + f0 + fl0);
        *(bf16x8*)(&sB[nn * 72 + fl0]) = b8;
      }
    }
    __syncthreads();

    // scores: wave wid owns f rows [wid*16, wid*16+16)
    f32x4 sacc[4];
    #pragma unroll
    for (int nt = 0; nt < 4; ++nt) sacc[nt] = zf;
    const int frow = wid * 16 + l15;
    const int swq = l15 & 7;
    #pragma unroll
    for (int kt = 0; kt < 8; ++kt) {
      int kb = kt * 4 + q4;
      bf16x8 a8 = *(const bf16x8*)(&sQ[frow * 256 + ((kb ^ swq) << 3)]);
      #pragma unroll
      for (int nt = 0; nt < 4; ++nt) {
        bf16x8 b8 = *(const bf16x8*)(&sK[(nt * 16 + l15) * 256 + ((kb ^ swq) << 3)]);
        sacc[nt] = __builtin_amdgcn_mfma_f32_16x16x32_bf16(a8, b8, sacc[nt], 0, 0, 0);
      }
    }

    // softmax over n=64
    #pragma unroll
    for (int r = 0; r < 4; ++r) {
      const int fcl = wid * 16 + q4 * 4 + r;
      float v[4];
      #pragma unroll
      for (int nt = 0; nt < 4; ++nt)
        v[nt] = sacc[nt][r] * ss + b2f(sB[(nt * 16 + l15) * 72 + fcl]) * ps;
      float mx = fmaxf(fmaxf(v[0], v[1]), fmaxf(v[2], v[3]));
      #pragma unroll
      for (int d = 1; d < 16; d <<= 1) mx = fmaxf(mx, __shfl_xor(mx, d));
      float e[4], sum = 0.f;
      #pragma unroll
      for (int nt = 0; nt < 4; ++nt) { e[nt] = __expf(v[nt] - mx); sum += e[nt]; }
      #pragma unroll
      for (int d = 1; d < 16; d <<= 1) sum += __shfl_xor(sum, d);
      float inv = 1.0f / sum;
      #pragma unroll
      for (int nt = 0; nt < 4; ++nt)
        sW[fcl * 72 + nt * 16 + l15] = f2b(e[nt] * inv);
    }
    __syncthreads();

    // PV: wave wid owns c rows [wid*64, wid*64+64)
    f32x4 pacc[4][4];
    #pragma unroll
    for (int mf = 0; mf < 4; ++mf)
      #pragma unroll
      for (int nf = 0; nf < 4; ++nf) pacc[mf][nf] = zf;
    #pragma unroll
    for (int kt = 0; kt < 2; ++kt) {
      int k0 = kt * 32 + q4 * 8;
      bf16x8 a8[4], b8[4];
      #pragma unroll
      for (int mf = 0; mf < 4; ++mf)
        a8[mf] = *(const bf16x8*)(&sV[(wid * 64 + mf * 16 + l15) * 72 + k0]);
      #pragma unroll
      for (int nf = 0; nf < 4; ++nf)
        b8[nf] = *(const bf16x8*)(&sW[(nf * 16 + l15) * 72 + k0]);
      #pragma unroll
      for (int mf = 0; mf < 4; ++mf)
        #pragma unroll
        for (int nf = 0; nf < 4; ++nf)
          pacc[mf][nf] = __builtin_amdgcn_mfma_f32_16x16x32_bf16(a8[mf], b8[nf], pacc[mf][nf], 0, 0, 0);
    }
    // O write, transposed [f][c], 8B per store
    #pragma unroll
    for (int mf = 0; mf < 4; ++mf) {
      int cb = wid * 64 + mf * 16 + q4 * 4;
      #pragma unroll
      for (int nf = 0; nf < 4; ++nf) {
        int f = f0 + nf * 16 + l15;
        bf16x4 pk;
        #pragma unroll
        for (int r = 0; r < 4; ++r) pk[r] = (short)f2b(pacc[mf][nf][r]);
        *(bf16x4*)(Ot + (size_t)f * C_ + cb) = pk;
      }
    }
    __syncthreads();
  }
}

// -------------------------------------------------------------------------
extern "C" void kernel_launch(void* const* d_in, const int* in_sizes, int n_in,
                              void* d_out, int out_size, void* d_ws, size_t ws_size,
                              hipStream_t stream)
{
  (void)in_sizes; (void)n_in; (void)out_size;
  const float* latent     = (const float*)d_in[0];
  const float* side       = (const float*)d_in[1];
  const float* basis      = (const float*)d_in[2];
  const float* lp_norm_w  = (const float*)d_in[3];
  const float* lp_w       = (const float*)d_in[4];
  const float* lp_b       = (const float*)d_in[5];
  const float* qn_w       = (const float*)d_in[6];
  const float* qmlp_in_w  = (const float*)d_in[7];
  const float* qmlp_in_b  = (const float*)d_in[8];
  const float* qmlp_out_w = (const float*)d_in[9];
  const float* qmlp_out_b = (const float*)d_in[10];
  const float* q_w        = (const float*)d_in[11];
  const float* q_b        = (const float*)d_in[12];
  const float* k_w        = (const float*)d_in[13];
  const float* k_b        = (const float*)d_in[14];
  const float* v_w        = (const float*)d_in[15];
  const float* v_b        = (const float*)d_in[16];
  const float* o_w        = (const float*)d_in[17];
  const float* o_b        = (const float*)d_in[18];
  const float* ffn_norm_w = (const float*)d_in[19];
  const float* ffn_in_w   = (const float*)d_in[20];
  const float* ffn_in_b   = (const float*)d_in[21];
  const float* ffn_out_w  = (const float*)d_in[22];
  const float* ffn_out_b  = (const float*)d_in[23];
  const float* sc_scale   = (const float*)d_in[24];
  const float* pr_scale   = (const float*)d_in[25];
  const float* qk_scale   = (const float*)d_in[26];
  float* out = (float*)d_out;

  // ---- workspace carve, chunk count chosen to FIT ws_size ----
  auto align256 = [](size_t b) { return (b + 255) & ~(size_t)255; };
  const size_t wsmall = align256((size_t)C_ * C_ * 2);
  const size_t fixed_bytes =
      7 * wsmall + 2 * align256((size_t)2 * C_ * C_ * 2) + align256((size_t)C_ * 4) +
      3 * align256((size_t)B_ * C_ * PLAT_ * 2);
  int nc = 16;
  for (int c = 1; c <= 16; c <<= 1) {
    size_t Pcb = (size_t)PSIDE_ / c;
    size_t need = fixed_bytes + 2 * align256((size_t)B_ * C_ * Pcb * 2);
    if (need <= ws_size) { nc = c; break; }
  }
  const int Pc  = PSIDE_ / nc;
  const int Tc  = T_ / nc;
  int ltc = 0; while ((1 << ltc) < Tc) ++ltc;   // log2(Tc)

  char* ws = (char*)d_ws;
  size_t off = 0;
  auto carve = [&](size_t bytes) -> char* {
    char* p = ws + off;
    off += (bytes + 255) & ~(size_t)255;
    return p;
  };
  unsigned short* wlp      = (unsigned short*)carve((size_t)C_ * C_ * 2);
  unsigned short* wqin     = (unsigned short*)carve((size_t)2 * C_ * C_ * 2);
  unsigned short* wffin    = (unsigned short*)carve((size_t)2 * C_ * C_ * 2);
  unsigned short* wk       = (unsigned short*)carve((size_t)C_ * C_ * 2);
  unsigned short* wv       = (unsigned short*)carve((size_t)C_ * C_ * 2);
  unsigned short* wo       = (unsigned short*)carve((size_t)C_ * C_ * 2);
  unsigned short* wqo      = (unsigned short*)carve((size_t)C_ * C_ * 2);
  unsigned short* wfo      = (unsigned short*)carve((size_t)C_ * C_ * 2);
  unsigned short* wqeff    = (unsigned short*)carve((size_t)C_ * C_ * 2);
  float*          beff     = (float*)carve((size_t)C_ * 4);
  unsigned short* latent_h = (unsigned short*)carve((size_t)B_ * C_ * PLAT_ * 2);
  unsigned short* kbuf     = (unsigned short*)carve((size_t)B_ * C_ * PLAT_ * 2);
  unsigned short* vbuf     = (unsigned short*)carve((size_t)B_ * C_ * PLAT_ * 2);
  unsigned short* big0     = (unsigned short*)carve((size_t)B_ * C_ * Pc * 2);
  unsigned short* qbuf     = (unsigned short*)carve((size_t)B_ * C_ * Pc * 2);
  float* qh = out;   // query_h lives in d_out until o-gemm RMWs it (same index)

  const dim3 blk(256);
  const dim3 gLat(PLAT_ / 128, C_ / 64, B_);
  const dim3 gCh(Pc / 128, C_ / 64, B_);
  const int NW = C_ * C_;   // 65536

  // weight prep: fold norm weights; convert plain weights to bf16; fold q chain
  wprep_k<<<dim3(NW / 256), blk, 0, stream>>>(lp_w, lp_norm_w, wlp, NW);
  wprep_k<<<dim3(2 * NW / 256), blk, 0, stream>>>(qmlp_in_w, qn_w, wqin, 2 * NW);
  wprep_k<<<dim3(2 * NW / 256), blk, 0, stream>>>(ffn_in_w, ffn_norm_w, wffin, 2 * NW);
  cvt_k<<<dim3(NW / 256), blk, 0, stream>>>(k_w, wk, NW);
  cvt_k<<<dim3(NW / 256), blk, 0, stream>>>(v_w, wv, NW);
  cvt_k<<<dim3(NW / 256), blk, 0, stream>>>(o_w, wo, NW);
  cvt_k<<<dim3(NW / 256), blk, 0, stream>>>(qmlp_out_w, wqo, NW);
  cvt_k<<<dim3(NW / 256), blk, 0, stream>>>(ffn_out_w, wfo, NW);
  foldw_k<<<dim3(C_), blk, 0, stream>>>(q_w, qmlp_out_w, wqeff);
  foldb_k<<<dim3(1), blk, 0, stream>>>(q_w, qmlp_out_b, q_b, beff);

  // latent path (once): rms fused into lp-gemm
  gemm_k<EPI_SILU, true, false, unsigned short, true><<<gLat, blk, 0, stream>>>(
      latent, wlp, lp_b, nullptr, latent_h, PLAT_, 0, PLAT_, 0);
  gemm_k<EPI_NONE, false, true, unsigned short, true><<<gLat, blk, 0, stream>>>(
      latent_h, wk, k_b, nullptr, kbuf, PLAT_, 0, PLAT_, 0);
  gemm_k<EPI_NONE, false, true, unsigned short, false><<<gLat, blk, 0, stream>>>(
      latent_h, wv, v_b, nullptr, vbuf, PLAT_, 0, PLAT_, 0);

  // side path, chunked over t
  for (int ch = 0; ch < nc; ++ch) {
    const int co = ch * Pc;
    const int t0 = ch * Tc;
    // big0 = swiglu_inner(qmlp_in @ rms(side))   [rms fused]
    gemm_k<EPI_SWIGLU, true, false, unsigned short, true><<<gCh, blk, 0, stream>>>(
        side, wqin, qmlp_in_b, nullptr, big0, PSIDE_, co, Pc, 0);
    // qh = qmlp_out @ big0   (fp32, lives in d_out; used by skip only)
    gemm_k<EPI_NONE, false, true, float, false><<<gCh, blk, 0, stream>>>(
        big0, wqo, qmlp_out_b, nullptr, qh, Pc, 0, PSIDE_, co);
    // qbuf = (q_w @ qmlp_out) @ big0 + folded bias
    gemm_k<EPI_NONE, false, true, unsigned short, true><<<gCh, blk, 0, stream>>>(
        big0, wqeff, beff, nullptr, qbuf, Pc, 0, Pc, 0);
    // attention in-place over qbuf
    attn_k<<<dim3(B_ * Tc), blk, 0, stream>>>(qbuf, kbuf, vbuf, basis, sc_scale, pr_scale,
                                              qbuf, Pc, t0, ltc);
    // out = o_w @ attended + o_b + qss*qh  (aliases qh: same-index RMW)
    gemm_k<EPI_SKIP, false, true, float, false><<<gCh, blk, 0, stream>>>(
        qbuf, wo, o_b, qk_scale, out, Pc, 0, PSIDE_, co);
    // FFN: rms fused into ffn-in
    gemm_k<EPI_SWIGLU, true, false, unsigned short, true><<<gCh, blk, 0, stream>>>(
        out, wffin, ffn_in_b, nullptr, big0, PSIDE_, co, Pc, 0);
    gemm_k<EPI_RESID, false, true, float, false><<<gCh, blk, 0, stream>>>(
        big0, wfo, ffn_out_b, nullptr, out, Pc, 0, PSIDE_, co);
  }
}

// Round 2
// 1620.897 us; speedup vs baseline: 1.1424x; 1.1348x over previous
//
#include <hip/hip_runtime.h>
#include <stdint.h>
#include <stddef.h>

#define B_ 4
#define C_ 256
#define T_ 128
#define NB_ 64
#define NF_ 512
#define PLAT_ (T_*NB_)    // 8192
#define PSIDE_ (T_*NF_)   // 65536

using bf16x8 = __attribute__((ext_vector_type(8))) short;
using bf16x4 = __attribute__((ext_vector_type(4))) short;
using f32x4  = __attribute__((ext_vector_type(4))) float;

__device__ __forceinline__ float b2f(unsigned short h) {
  unsigned int u = ((unsigned int)h) << 16;
  return __builtin_bit_cast(float, u);
}
__device__ __forceinline__ unsigned short f2b(float f) {
  unsigned int u = __builtin_bit_cast(unsigned int, f);
  u += 0x7FFFu + ((u >> 16) & 1u);
  return (unsigned short)(u >> 16);
}

__device__ __forceinline__ bf16x8 ld8(const unsigned short* p) {
  return *(const bf16x8*)p;
}
__device__ __forceinline__ bf16x8 ld8(const float* p) {
  float4 a = *(const float4*)p;
  float4 b = *(const float4*)(p + 4);
  bf16x8 r;
  r[0] = (short)f2b(a.x); r[1] = (short)f2b(a.y);
  r[2] = (short)f2b(a.z); r[3] = (short)f2b(a.w);
  r[4] = (short)f2b(b.x); r[5] = (short)f2b(b.y);
  r[6] = (short)f2b(b.z); r[7] = (short)f2b(b.w);
  return r;
}
__device__ __forceinline__ float ldv(float v) { return v; }
__device__ __forceinline__ float ldv(unsigned short v) { return b2f(v); }
__device__ __forceinline__ void stv(float* p, float v) { *p = v; }
__device__ __forceinline__ void stv(unsigned short* p, float v) { *p = f2b(v); }

// async global->LDS, 16B per lane; lds dst must be wave-uniform base (lane*16 added by HW)
__device__ __forceinline__ void gload16(const void* g, void* l) {
  __builtin_amdgcn_global_load_lds(
      (const __attribute__((address_space(1))) void*)g,
      (__attribute__((address_space(3))) void*)l, 16, 0, 0);
}

enum { EPI_NONE = 0, EPI_SILU = 1, EPI_RESID = 3, EPI_SWIGLU = 4, EPI_DUALX = 5 };

// fold per-channel norm weight into conv weight (fp32 in, bf16 out)
__global__ __launch_bounds__(256) void wprep_k(const float* __restrict__ w,
                                               const float* __restrict__ nw,
                                               unsigned short* __restrict__ out, int n)
{
  int i = blockIdx.x * 256 + threadIdx.x;
  if (i < n) out[i] = f2b(w[i] * nw[i & 255]);
}

// plain fp32 -> bf16 convert
__global__ __launch_bounds__(256) void cvt_k(const float* __restrict__ in,
                                             unsigned short* __restrict__ out, int n)
{
  int i = blockIdx.x * 256 + threadIdx.x;
  if (i < n) out[i] = f2b(in[i]);
}

// scaled convert: out[i] = bf16(w[i] * s[0])
__global__ __launch_bounds__(256) void wscale_k(const float* __restrict__ w,
                                                const float* __restrict__ s,
                                                unsigned short* __restrict__ out, int n)
{
  int i = blockIdx.x * 256 + threadIdx.x;
  if (i < n) out[i] = f2b(w[i] * s[0]);
}

// weight fold: out[m][c] = bf16( sum_j A[m][j] * Bm[j][c] )  (q_w @ qmlp_out)
__global__ __launch_bounds__(256) void foldw_k(const float* __restrict__ A,
                                               const float* __restrict__ Bm,
                                               unsigned short* __restrict__ out)
{
  const int m = blockIdx.x;
  const int c = threadIdx.x;
  float acc = 0.f;
  #pragma unroll 8
  for (int j = 0; j < C_; ++j) acc = fmaf(A[m * C_ + j], Bm[j * C_ + c], acc);
  out[m * C_ + c] = f2b(acc);
}

// bias fold: bout[m] = sum_j A[m][j]*bin[j] + badd[m]
__global__ __launch_bounds__(256) void foldb_k(const float* __restrict__ A,
                                               const float* __restrict__ bin,
                                               const float* __restrict__ badd,
                                               float* __restrict__ bout)
{
  const int m = threadIdx.x;
  float acc = 0.f;
  #pragma unroll 8
  for (int j = 0; j < C_; ++j) acc = fmaf(A[m * C_ + j], bin[j], acc);
  bout[m] = acc + badd[m];
}

// bias combine: bout[m] = b0[m] + s[0]*b1[m]
__global__ __launch_bounds__(256) void bcomb_k(const float* __restrict__ b0,
                                               const float* __restrict__ b1,
                                               const float* __restrict__ s,
                                               float* __restrict__ bout)
{
  const int m = threadIdx.x;
  bout[m] = b0[m] + s[0] * b1[m];
}

// -------------------------------------------------------------------------
// GEMM over channels. X layouts:
//  XT=true : X bf16 transposed [z][pix][C_] -> global_load_lds (linear dest,
//            source chunk pre-swizzled)
//  XT=false: X fp32 [z][C_][Xs] -> k-major per-thread loads (8 consecutive k
//            for one pixel), pack to bf16x8, ONE ds_write_b128 per pixel row.
//            RMS may be fused (per-pixel sumsq accumulated during staging).
// LDS sX layout: row n (pixel) has 4 16B k-chunks; global chunk c lives in
// slot c ^ u(n), u(n) = (n&3) ^ ((n>>2)&1). Conflict-free b128 read+write.
// EPI_SWIGLU: two W banks (a,g), one X.  EPI_DUALX: two X, two W banks,
// single accumulator (Y = W0@X0 + W1@X1 + bias; scale pre-folded into W1).
// BM=64, BN=128, BK=32, 4 waves.
template<int EPI, bool RMS, bool XT, typename TY, bool YT>
__global__ __launch_bounds__(256) void gemm_k(
    const void* __restrict__ Xv,
    const void* __restrict__ Xv2,
    const unsigned short* __restrict__ W,
    const float* __restrict__ bias,
    TY* Y,
    int Xs, int Xoff, int Ys, int Yoff)
{
  constexpr bool WDUAL = (EPI == EPI_SWIGLU) || (EPI == EPI_DUALX);
  constexpr bool GDUAL = (EPI == EPI_SWIGLU);   // second accumulator
  constexpr bool XDUAL = (EPI == EPI_DUALX);
  __shared__ unsigned short sA[WDUAL ? 2 : 1][64 * 40];
  __shared__ unsigned short sX[XDUAL ? 2 : 1][128 * 32];

  const int tid = threadIdx.x;
  const int lane = tid & 63;
  const int wid = tid >> 6;
  const int l15 = lane & 15;
  const int q4 = lane >> 4;
  const int z = blockIdx.z;
  const int p0 = blockIdx.x * 128;
  const int m0 = blockIdx.y * 64;
  const int mh = wid >> 1, nh = wid & 1;

  const float* Xf = nullptr;
  const unsigned short* Xt = nullptr;
  const unsigned short* Xt2 = nullptr;
  if constexpr (XT) {
    Xt = (const unsigned short*)Xv + ((size_t)z * Xs + Xoff + p0) * C_;
    if constexpr (XDUAL)
      Xt2 = (const unsigned short*)Xv2 + ((size_t)z * Xs + Xoff + p0) * C_;
  } else {
    Xf = (const float*)Xv + (size_t)z * C_ * Xs + Xoff + p0;
  }

  const f32x4 zf = {0.f, 0.f, 0.f, 0.f};
  f32x4 acc0[2][4];
  f32x4 acc1[GDUAL ? 2 : 1][4];
  #pragma unroll
  for (int i = 0; i < 2; ++i)
    #pragma unroll
    for (int j = 0; j < 4; ++j) { acc0[i][j] = zf; if constexpr (GDUAL) acc1[i][j] = zf; }

  // W staging map
  const int arow = tid >> 2;
  const int acol = (tid & 3) << 3;
  // XT staging map: lane L stages row rbase+(L>>2), slot L&3 <- global chunk
  // c = (L&3) ^ u(n), u(n) = (n&3)^((n>>2)&1) = ((L>>2)&3)^((L>>4)&1)
  const int schunk = (lane & 3) ^ ((lane >> 2) & 3) ^ ((lane >> 4) & 1);
  // fp32 k-major map: wave wid stages k rows [wid*8,wid*8+8), pixels n=lane, n=64+lane
  const int wslot = (wid ^ (lane & 3) ^ ((lane >> 2) & 1)) << 4;
  const int wa0 = lane * 64 + wslot;
  const int wa1 = wa0 + 64 * 64;
  // MFMA B-frag read swizzle (n = nh*64 + nf*16 + l15 -> u(n) lane-constant)
  const int un = (l15 & 3) ^ ((l15 >> 2) & 1);

  float sq0 = 0.f, sq1 = 0.f;

  for (int kt = 0; kt < 8; ++kt) {
    if constexpr (XT) {
      #pragma unroll
      for (int j2 = 0; j2 < 2; ++j2) {
        int rbase = wid * 32 + j2 * 16;
        const size_t srcoff = (size_t)(rbase + (lane >> 2)) * C_ + kt * 32 + (schunk << 3);
        gload16(Xt + srcoff, &sX[0][rbase * 32]);
        if constexpr (XDUAL) gload16(Xt2 + srcoff, &sX[1][rbase * 32]);
      }
    } else {
      const float* xp = Xf + (size_t)(kt * 32 + wid * 8) * Xs;
      float v0[8], v1[8];
      #pragma unroll
      for (int j = 0; j < 8; ++j) {
        v0[j] = xp[(size_t)j * Xs + lane];
        v1[j] = xp[(size_t)j * Xs + 64 + lane];
      }
      bf16x8 w0, w1;
      #pragma unroll
      for (int j = 0; j < 8; ++j) {
        if constexpr (RMS) { sq0 = fmaf(v0[j], v0[j], sq0); sq1 = fmaf(v1[j], v1[j], sq1); }
        w0[j] = (short)f2b(v0[j]);
        w1[j] = (short)f2b(v1[j]);
      }
      *(bf16x8*)((char*)&sX[0][0] + wa0) = w0;
      *(bf16x8*)((char*)&sX[0][0] + wa1) = w1;
    }
    // stage weights 64x32
    {
      bf16x8 a8 = ld8(W + (size_t)(m0 + arow) * C_ + kt * 32 + acol);
      *(bf16x8*)(&sA[0][arow * 40 + acol]) = a8;
      if constexpr (WDUAL) {
        bf16x8 a8b = ld8(W + (size_t)(C_ + m0 + arow) * C_ + kt * 32 + acol);
        *(bf16x8*)(&sA[1][arow * 40 + acol]) = a8b;
      }
    }
    __syncthreads();

    bf16x8 af0[2], af1[2], bfr[4], bfr2[4];
    #pragma unroll
    for (int mf = 0; mf < 2; ++mf) {
      int row = mh * 32 + mf * 16 + l15;
      af0[mf] = *(const bf16x8*)(&sA[0][row * 40 + q4 * 8]);
      if constexpr (WDUAL) af1[mf] = *(const bf16x8*)(&sA[1][row * 40 + q4 * 8]);
    }
    #pragma unroll
    for (int nf = 0; nf < 4; ++nf) {
      int n = nh * 64 + nf * 16 + l15;
      bfr[nf] = *(const bf16x8*)(&sX[0][n * 32 + ((q4 ^ un) << 3)]);
      if constexpr (XDUAL)
        bfr2[nf] = *(const bf16x8*)(&sX[1][n * 32 + ((q4 ^ un) << 3)]);
    }
    #pragma unroll
    for (int mf = 0; mf < 2; ++mf)
      #pragma unroll
      for (int nf = 0; nf < 4; ++nf) {
        acc0[mf][nf] = __builtin_amdgcn_mfma_f32_16x16x32_bf16(af0[mf], bfr[nf], acc0[mf][nf], 0, 0, 0);
        if constexpr (GDUAL)
          acc1[mf][nf] = __builtin_amdgcn_mfma_f32_16x16x32_bf16(af1[mf], bfr[nf], acc1[mf][nf], 0, 0, 0);
        if constexpr (XDUAL)
          acc0[mf][nf] = __builtin_amdgcn_mfma_f32_16x16x32_bf16(af1[mf], bfr2[nf], acc0[mf][nf], 0, 0, 0);
      }
    __syncthreads();
  }

  // fused RMS colscale (per-pixel partial sums already per-(wid,n))
  float cs[4] = {1.f, 1.f, 1.f, 1.f};
  if constexpr (RMS) {
    __shared__ float red[4][128];
    red[wid][lane] = sq0;
    red[wid][64 + lane] = sq1;
    __syncthreads();
    #pragma unroll
    for (int nf = 0; nf < 4; ++nf) {
      int n = nh * 64 + nf * 16 + l15;
      cs[nf] = rsqrtf((red[0][n] + red[1][n] + red[2][n] + red[3][n]) * (1.0f / (float)C_) + 1e-6f);
    }
  }

  // epilogue
  TY* Yb = nullptr;
  if constexpr (!YT) Yb = Y + (size_t)z * C_ * Ys + Yoff;

  #pragma unroll
  for (int mf = 0; mf < 2; ++mf) {
    const int mb = m0 + mh * 32 + mf * 16 + q4 * 4;
    const float4 b1 = *(const float4*)(bias + mb);
    float4 b2 = {0.f, 0.f, 0.f, 0.f};
    if constexpr (GDUAL) b2 = *(const float4*)(bias + C_ + mb);
    #pragma unroll
    for (int nf = 0; nf < 4; ++nf) {
      const int pl = p0 + nh * 64 + nf * 16 + l15;
      if constexpr (YT) {
        bf16x4 pk;
        #pragma unroll
        for (int r = 0; r < 4; ++r) {
          float y = acc0[mf][nf][r] * cs[nf] + ((const float*)&b1)[r];
          if constexpr (EPI == EPI_SILU) y = y / (1.0f + __expf(-y));
          if constexpr (EPI == EPI_SWIGLU) {
            float g = acc1[mf][nf][r] * cs[nf] + ((const float*)&b2)[r];
            y = y * (g / (1.0f + __expf(-g)));
          }
          pk[r] = (short)f2b(y);
        }
        *(bf16x4*)(Y + ((size_t)z * Ys + Yoff + pl) * C_ + mb) = pk;
      } else {
        #pragma unroll
        for (int r = 0; r < 4; ++r) {
          size_t oidx = (size_t)(mb + r) * Ys + pl;
          float y = acc0[mf][nf][r] * cs[nf] + ((const float*)&b1)[r];
          if constexpr (EPI == EPI_SILU) y = y / (1.0f + __expf(-y));
          if constexpr (EPI == EPI_SWIGLU) {
            float g = acc1[mf][nf][r] * cs[nf] + ((const float*)&b2)[r];
            y = y * (g / (1.0f + __expf(-g)));
          }
          if constexpr (EPI == EPI_RESID) y += ldv(Yb[oidx]);
          stv(&Yb[oidx], y);
        }
      }
    }
  }
}

// -------------------------------------------------------------------------
// Fused cross-attention, one block per (z, t_local).
// Q, K transposed bf16 [pix][C_]; V non-transposed [C_][pix]; O transposed (in-place on Q buf).
// sK/sQ: linear [64][256] with 8-way chunk XOR: slot s of row n holds chunk s ^ (n&7).
__global__ __launch_bounds__(256) void attn_k(
    const unsigned short* Q,
    const unsigned short* __restrict__ Kp,
    const unsigned short* __restrict__ Vp,
    const float* __restrict__ basis,
    const float* __restrict__ ssp,
    const float* __restrict__ psp,
    unsigned short* O,
    int PsQ, int t0, int ltc)
{
  __shared__ unsigned short sK[64 * 256];
  __shared__ unsigned short sQ[64 * 256];
  __shared__ unsigned short sV[256 * 72];   // [c][n] (A-operand)
  __shared__ unsigned short sW[64 * 72];    // [f][n] softmax weights (B-operand)
  __shared__ unsigned short sB[64 * 72];    // [n][f] bias chunk

  const int tid = threadIdx.x;
  const int lane = tid & 63;
  const int wid = tid >> 6;
  const int l15 = lane & 15;
  const int q4 = lane >> 4;
  const int z = blockIdx.x >> ltc;
  const int tl = blockIdx.x & ((1 << ltc) - 1);

  const unsigned short* Qt = Q + ((size_t)z * PsQ + (size_t)tl * NF_) * C_;
  unsigned short*       Ot = O + ((size_t)z * PsQ + (size_t)tl * NF_) * C_;
  const unsigned short* Kt = Kp + ((size_t)z * PLAT_ + (size_t)(t0 + tl) * NB_) * C_;
  const size_t vbase = (size_t)z * C_ * PLAT_ + (size_t)(t0 + tl) * NB_;

  const float ss = ssp[0];
  const float ps = psp[0];
  const f32x4 zf = {0.f, 0.f, 0.f, 0.f};

  // stage K (gload_lds, swizzled) and V (reg path) once per block
  {
    #pragma unroll
    for (int it = 0; it < 8; ++it) {
      int i = wid * 8 + it;
      int n = 2 * i + (lane >> 5);
      int sc = (lane & 31) ^ (n & 7);
      gload16(Kt + (size_t)n * C_ + (sc << 3), &sK[i * 512]);
    }
    const int c0 = tid >> 3;
    const int n0 = (tid & 7) << 3;
    #pragma unroll
    for (int pass = 0; pass < 8; ++pass) {
      int c = c0 + pass * 32;
      bf16x8 v8 = *(const bf16x8*)(Vp + vbase + (size_t)c * PLAT_ + n0);
      *(bf16x8*)(&sV[c * 72 + n0]) = v8;
    }
  }

  for (int fc = 0; fc < 8; ++fc) {
    const int f0 = fc * 64;
    // stage Q chunk (gload_lds, swizzled) and fp32 bias chunk [n][f]
    #pragma unroll
    for (int it = 0; it < 8; ++it) {
      int i = wid * 8 + it;
      int n = 2 * i + (lane >> 5);
      int sc = (lane & 31) ^ (n & 7);
      gload16(Qt + (size_t)(f0 + n) * C_ + (sc << 3), &sQ[i * 512]);
    }
    {
      const int nr = tid >> 3;
      const int fl0 = (tid & 7) << 3;
      #pragma unroll
      for (int pass = 0; pass < 2; ++pass) {
        int nn = nr + pass * 32;
        bf16x8 b8 = ld8(basis + (size_t)nn * NF_ + f0 + fl0);
        *(bf16x8*)(&sB[nn * 72 + fl0]) = b8;
      }
    }
    __syncthreads();

    // scores: wave wid owns f rows [wid*16, wid*16+16)
    f32x4 sacc[4];
    #pragma unroll
    for (int nt = 0; nt < 4; ++nt) sacc[nt] = zf;
    const int frow = wid * 16 + l15;
    const int swq = l15 & 7;
    #pragma unroll
    for (int kt = 0; kt < 8; ++kt) {
      int kb = kt * 4 + q4;
      bf16x8 a8 = *(const bf16x8*)(&sQ[frow * 256 + ((kb ^ swq) << 3)]);
      #pragma unroll
      for (int nt = 0; nt < 4; ++nt) {
        bf16x8 b8 = *(const bf16x8*)(&sK[(nt * 16 + l15) * 256 + ((kb ^ swq) << 3)]);
        sacc[nt] = __builtin_amdgcn_mfma_f32_16x16x32_bf16(a8, b8, sacc[nt], 0, 0, 0);
      }
    }

    // softmax over n=64
    #pragma unroll
    for (int r = 0; r < 4; ++r) {
      const int fcl = wid * 16 + q4 * 4 + r;
      float v[4];
      #pragma unroll
      for (int nt = 0; nt < 4; ++nt)
        v[nt] = sacc[nt][r] * ss + b2f(sB[(nt * 16 + l15) * 72 + fcl]) * ps;
      float mx = fmaxf(fmaxf(v[0], v[1]), fmaxf(v[2], v[3]));
      #pragma unroll
      for (int d = 1; d < 16; d <<= 1) mx = fmaxf(mx, __shfl_xor(mx, d));
      float e[4], sum = 0.f;
      #pragma unroll
      for (int nt = 0; nt < 4; ++nt) { e[nt] = __expf(v[nt] - mx); sum += e[nt]; }
      #pragma unroll
      for (int d = 1; d < 16; d <<= 1) sum += __shfl_xor(sum, d);
      float inv = 1.0f / sum;
      #pragma unroll
      for (int nt = 0; nt < 4; ++nt)
        sW[fcl * 72 + nt * 16 + l15] = f2b(e[nt] * inv);
    }
    __syncthreads();

    // PV: wave wid owns c rows [wid*64, wid*64+64)
    f32x4 pacc[4][4];
    #pragma unroll
    for (int mf = 0; mf < 4; ++mf)
      #pragma unroll
      for (int nf = 0; nf < 4; ++nf) pacc[mf][nf] = zf;
    #pragma unroll
    for (int kt = 0; kt < 2; ++kt) {
      int k0 = kt * 32 + q4 * 8;
      bf16x8 a8[4], b8[4];
      #pragma unroll
      for (int mf = 0; mf < 4; ++mf)
        a8[mf] = *(const bf16x8*)(&sV[(wid * 64 + mf * 16 + l15) * 72 + k0]);
      #pragma unroll
      for (int nf = 0; nf < 4; ++nf)
        b8[nf] = *(const bf16x8*)(&sW[(nf * 16 + l15) * 72 + k0]);
      #pragma unroll
      for (int mf = 0; mf < 4; ++mf)
        #pragma unroll
        for (int nf = 0; nf < 4; ++nf)
          pacc[mf][nf] = __builtin_amdgcn_mfma_f32_16x16x32_bf16(a8[mf], b8[nf], pacc[mf][nf], 0, 0, 0);
    }
    // O write, transposed [f][c], 8B per store
    #pragma unroll
    for (int mf = 0; mf < 4; ++mf) {
      int cb = wid * 64 + mf * 16 + q4 * 4;
      #pragma unroll
      for (int nf = 0; nf < 4; ++nf) {
        int f = f0 + nf * 16 + l15;
        bf16x4 pk;
        #pragma unroll
        for (int r = 0; r < 4; ++r) pk[r] = (short)f2b(pacc[mf][nf][r]);
        *(bf16x4*)(Ot + (size_t)f * C_ + cb) = pk;
      }
    }
    __syncthreads();
  }
}

// -------------------------------------------------------------------------
extern "C" void kernel_launch(void* const* d_in, const int* in_sizes, int n_in,
                              void* d_out, int out_size, void* d_ws, size_t ws_size,
                              hipStream_t stream)
{
  (void)in_sizes; (void)n_in; (void)out_size;
  const float* latent     = (const float*)d_in[0];
  const float* side       = (const float*)d_in[1];
  const float* basis      = (const float*)d_in[2];
  const float* lp_norm_w  = (const float*)d_in[3];
  const float* lp_w       = (const float*)d_in[4];
  const float* lp_b       = (const float*)d_in[5];
  const float* qn_w       = (const float*)d_in[6];
  const float* qmlp_in_w  = (const float*)d_in[7];
  const float* qmlp_in_b  = (const float*)d_in[8];
  const float* qmlp_out_w = (const float*)d_in[9];
  const float* qmlp_out_b = (const float*)d_in[10];
  const float* q_w        = (const float*)d_in[11];
  const float* q_b        = (const float*)d_in[12];
  const float* k_w        = (const float*)d_in[13];
  const float* k_b        = (const float*)d_in[14];
  const float* v_w        = (const float*)d_in[15];
  const float* v_b        = (const float*)d_in[16];
  const float* o_w        = (const float*)d_in[17];
  const float* o_b        = (const float*)d_in[18];
  const float* ffn_norm_w = (const float*)d_in[19];
  const float* ffn_in_w   = (const float*)d_in[20];
  const float* ffn_in_b   = (const float*)d_in[21];
  const float* ffn_out_w  = (const float*)d_in[22];
  const float* ffn_out_b  = (const float*)d_in[23];
  const float* sc_scale   = (const float*)d_in[24];
  const float* pr_scale   = (const float*)d_in[25];
  const float* qk_scale   = (const float*)d_in[26];
  float* out = (float*)d_out;

  // ---- workspace carve, chunk count chosen to FIT ws_size ----
  auto align256 = [](size_t b) { return (b + 255) & ~(size_t)255; };
  const size_t wsmall = align256((size_t)C_ * C_ * 2);
  const size_t fixed_bytes =
      4 * wsmall + 3 * align256((size_t)2 * C_ * C_ * 2) + 2 * align256((size_t)C_ * 4) +
      3 * align256((size_t)B_ * C_ * PLAT_ * 2);
  int nc = 16;
  for (int c = 1; c <= 16; c <<= 1) {
    size_t Pcb = (size_t)PSIDE_ / c;
    size_t need = fixed_bytes + 2 * align256((size_t)B_ * C_ * Pcb * 2);
    if (need <= ws_size) { nc = c; break; }
  }
  const int Pc  = PSIDE_ / nc;
  const int Tc  = T_ / nc;
  int ltc = 0; while ((1 << ltc) < Tc) ++ltc;   // log2(Tc)

  char* ws = (char*)d_ws;
  size_t off = 0;
  auto carve = [&](size_t bytes) -> char* {
    char* p = ws + off;
    off += (bytes + 255) & ~(size_t)255;
    return p;
  };
  unsigned short* wlp      = (unsigned short*)carve((size_t)C_ * C_ * 2);
  unsigned short* wqin     = (unsigned short*)carve((size_t)2 * C_ * C_ * 2);
  unsigned short* wffin    = (unsigned short*)carve((size_t)2 * C_ * C_ * 2);
  unsigned short* wk       = (unsigned short*)carve((size_t)C_ * C_ * 2);
  unsigned short* wv       = (unsigned short*)carve((size_t)C_ * C_ * 2);
  unsigned short* wfo      = (unsigned short*)carve((size_t)C_ * C_ * 2);
  unsigned short* wqeff    = (unsigned short*)carve((size_t)C_ * C_ * 2);
  unsigned short* wocat    = (unsigned short*)carve((size_t)2 * C_ * C_ * 2);  // [o_w ; qss*qmlp_out_w]
  float*          beff     = (float*)carve((size_t)C_ * 4);
  float*          bcomb    = (float*)carve((size_t)C_ * 4);
  unsigned short* latent_h = (unsigned short*)carve((size_t)B_ * C_ * PLAT_ * 2);
  unsigned short* kbuf     = (unsigned short*)carve((size_t)B_ * C_ * PLAT_ * 2);
  unsigned short* vbuf     = (unsigned short*)carve((size_t)B_ * C_ * PLAT_ * 2);
  unsigned short* big0     = (unsigned short*)carve((size_t)B_ * C_ * Pc * 2);
  unsigned short* qbuf     = (unsigned short*)carve((size_t)B_ * C_ * Pc * 2);

  const dim3 blk(256);
  const dim3 gLat(PLAT_ / 128, C_ / 64, B_);
  const dim3 gCh(Pc / 128, C_ / 64, B_);
  const int NW = C_ * C_;   // 65536

  // weight prep
  wprep_k<<<dim3(NW / 256), blk, 0, stream>>>(lp_w, lp_norm_w, wlp, NW);
  wprep_k<<<dim3(2 * NW / 256), blk, 0, stream>>>(qmlp_in_w, qn_w, wqin, 2 * NW);
  wprep_k<<<dim3(2 * NW / 256), blk, 0, stream>>>(ffn_in_w, ffn_norm_w, wffin, 2 * NW);
  cvt_k<<<dim3(NW / 256), blk, 0, stream>>>(k_w, wk, NW);
  cvt_k<<<dim3(NW / 256), blk, 0, stream>>>(v_w, wv, NW);
  cvt_k<<<dim3(NW / 256), blk, 0, stream>>>(ffn_out_w, wfo, NW);
  foldw_k<<<dim3(C_), blk, 0, stream>>>(q_w, qmlp_out_w, wqeff);
  foldb_k<<<dim3(1), blk, 0, stream>>>(q_w, qmlp_out_b, q_b, beff);
  cvt_k<<<dim3(NW / 256), blk, 0, stream>>>(o_w, wocat, NW);
  wscale_k<<<dim3(NW / 256), blk, 0, stream>>>(qmlp_out_w, qk_scale, wocat + (size_t)NW, NW);
  bcomb_k<<<dim3(1), blk, 0, stream>>>(o_b, qmlp_out_b, qk_scale, bcomb);

  // latent path (once): rms fused into lp-gemm
  gemm_k<EPI_SILU, true, false, unsigned short, true><<<gLat, blk, 0, stream>>>(
      latent, nullptr, wlp, lp_b, latent_h, PLAT_, 0, PLAT_, 0);
  gemm_k<EPI_NONE, false, true, unsigned short, true><<<gLat, blk, 0, stream>>>(
      latent_h, nullptr, wk, k_b, kbuf, PLAT_, 0, PLAT_, 0);
  gemm_k<EPI_NONE, false, true, unsigned short, false><<<gLat, blk, 0, stream>>>(
      latent_h, nullptr, wv, v_b, vbuf, PLAT_, 0, PLAT_, 0);

  // side path, chunked over t
  for (int ch = 0; ch < nc; ++ch) {
    const int co = ch * Pc;
    const int t0 = ch * Tc;
    // big0 = swiglu_inner(qmlp_in @ rms(side))   [rms fused]
    gemm_k<EPI_SWIGLU, true, false, unsigned short, true><<<gCh, blk, 0, stream>>>(
        side, nullptr, wqin, qmlp_in_b, big0, PSIDE_, co, Pc, 0);
    // qbuf = (q_w @ qmlp_out) @ big0 + folded bias
    gemm_k<EPI_NONE, false, true, unsigned short, true><<<gCh, blk, 0, stream>>>(
        big0, nullptr, wqeff, beff, qbuf, Pc, 0, Pc, 0);
    // attention in-place over qbuf
    attn_k<<<dim3(B_ * Tc), blk, 0, stream>>>(qbuf, kbuf, vbuf, basis, sc_scale, pr_scale,
                                              qbuf, Pc, t0, ltc);
    // out = o_w @ attended + qss*(qmlp_out @ big0) + (o_b + qss*qmlp_out_b)
    gemm_k<EPI_DUALX, false, true, float, false><<<gCh, blk, 0, stream>>>(
        qbuf, big0, wocat, bcomb, out, Pc, 0, PSIDE_, co);
    // FFN: rms fused into ffn-in
    gemm_k<EPI_SWIGLU, true, false, unsigned short, true><<<gCh, blk, 0, stream>>>(
        out, nullptr, wffin, ffn_in_b, big0, PSIDE_, co, Pc, 0);
    gemm_k<EPI_RESID, false, true, float, false><<<gCh, blk, 0, stream>>>(
        big0, nullptr, wfo, ffn_out_b, out, Pc, 0, PSIDE_, co);
  }
}

// Round 4
// 1456.879 us; speedup vs baseline: 1.2710x; 1.1126x over previous
//
#include <hip/hip_runtime.h>
#include <stdint.h>
#include <stddef.h>

#define B_ 4
#define C_ 256
#define T_ 128
#define NB_ 64
#define NF_ 512
#define PLAT_ (T_*NB_)    // 8192
#define PSIDE_ (T_*NF_)   // 65536

using bf16x8 = __attribute__((ext_vector_type(8))) short;
using bf16x4 = __attribute__((ext_vector_type(4))) short;
using f32x4  = __attribute__((ext_vector_type(4))) float;

__device__ __forceinline__ float b2f(unsigned short h) {
  unsigned int u = ((unsigned int)h) << 16;
  return __builtin_bit_cast(float, u);
}
__device__ __forceinline__ unsigned short f2b(float f) {
  unsigned int u = __builtin_bit_cast(unsigned int, f);
  u += 0x7FFFu + ((u >> 16) & 1u);
  return (unsigned short)(u >> 16);
}

__device__ __forceinline__ bf16x8 ld8(const unsigned short* p) {
  return *(const bf16x8*)p;
}
__device__ __forceinline__ bf16x8 ld8(const float* p) {
  float4 a = *(const float4*)p;
  float4 b = *(const float4*)(p + 4);
  bf16x8 r;
  r[0] = (short)f2b(a.x); r[1] = (short)f2b(a.y);
  r[2] = (short)f2b(a.z); r[3] = (short)f2b(a.w);
  r[4] = (short)f2b(b.x); r[5] = (short)f2b(b.y);
  r[6] = (short)f2b(b.z); r[7] = (short)f2b(b.w);
  return r;
}
__device__ __forceinline__ float ldv(float v) { return v; }
__device__ __forceinline__ float ldv(unsigned short v) { return b2f(v); }
__device__ __forceinline__ void stv(float* p, float v) { *p = v; }
__device__ __forceinline__ void stv(unsigned short* p, float v) { *p = f2b(v); }

// async global->LDS, 16B per lane; lds dst must be wave-uniform base (lane*16 added by HW)
__device__ __forceinline__ void gload16(const void* g, void* l) {
  __builtin_amdgcn_global_load_lds(
      (const __attribute__((address_space(1))) void*)g,
      (__attribute__((address_space(3))) void*)l, 16, 0, 0);
}

// chunk-XOR swizzle selector for 4x16B rows; note u4i(r + 128k) == u4i(r)
__device__ __forceinline__ int u4i(int r) { return (r ^ (r >> 2)) & 3; }

enum { EPI_NONE = 0, EPI_SILU = 1, EPI_RESID = 3, EPI_SWIGLU = 4, EPI_DUALX = 5 };

// fold per-channel norm weight into conv weight (fp32 in, bf16 out)
__global__ __launch_bounds__(256) void wprep_k(const float* __restrict__ w,
                                               const float* __restrict__ nw,
                                               unsigned short* __restrict__ out, int n)
{
  int i = blockIdx.x * 256 + threadIdx.x;
  if (i < n) out[i] = f2b(w[i] * nw[i & 255]);
}

// plain fp32 -> bf16 convert
__global__ __launch_bounds__(256) void cvt_k(const float* __restrict__ in,
                                             unsigned short* __restrict__ out, int n)
{
  int i = blockIdx.x * 256 + threadIdx.x;
  if (i < n) out[i] = f2b(in[i]);
}

// scaled convert: out[i] = bf16(w[i] * s[0])
__global__ __launch_bounds__(256) void wscale_k(const float* __restrict__ w,
                                                const float* __restrict__ s,
                                                unsigned short* __restrict__ out, int n)
{
  int i = blockIdx.x * 256 + threadIdx.x;
  if (i < n) out[i] = f2b(w[i] * s[0]);
}

// weight fold: out[m][c] = bf16( sum_j A[m][j] * Bm[j][c] )  (q_w @ qmlp_out)
__global__ __launch_bounds__(256) void foldw_k(const float* __restrict__ A,
                                               const float* __restrict__ Bm,
                                               unsigned short* __restrict__ out)
{
  const int m = blockIdx.x;
  const int c = threadIdx.x;
  float acc = 0.f;
  #pragma unroll 8
  for (int j = 0; j < C_; ++j) acc = fmaf(A[m * C_ + j], Bm[j * C_ + c], acc);
  out[m * C_ + c] = f2b(acc);
}

// bias fold: bout[m] = sum_j A[m][j]*bin[j] + badd[m]
__global__ __launch_bounds__(256) void foldb_k(const float* __restrict__ A,
                                               const float* __restrict__ bin,
                                               const float* __restrict__ badd,
                                               float* __restrict__ bout)
{
  const int m = threadIdx.x;
  float acc = 0.f;
  #pragma unroll 8
  for (int j = 0; j < C_; ++j) acc = fmaf(A[m * C_ + j], bin[j], acc);
  bout[m] = acc + badd[m];
}

// bias combine: bout[m] = b0[m] + s[0]*b1[m]
__global__ __launch_bounds__(256) void bcomb_k(const float* __restrict__ b0,
                                               const float* __restrict__ b1,
                                               const float* __restrict__ s,
                                               float* __restrict__ bout)
{
  const int m = threadIdx.x;
  bout[m] = b0[m] + s[0] * b1[m];
}

// -------------------------------------------------------------------------
// GEMM over channels, tall-M blocks (no m-redundancy on X reads).
// CFG 0: BM=256 (grid.y=1), 4 waves on M, BN=64 (wave tile 64x64).
// CFG 1: BM=128 (grid.y=2), 2x2 waves, BN=64 (wave tile 64x32) - for dual-acc.
// X layouts:
//  XT=true : X bf16 transposed [z][pix][C_] -> global_load_lds, source-swizzled
//  XT=false: X fp32 [z][C_][Xs] -> k-major per-thread loads (8 k, 1 pixel),
//            pack bf16x8, one ds_write_b128. RMS fused via per-pixel sumsq.
// W staged via global_load_lds (bf16, row-major), source-swizzled.
// LDS rows: 64B = 4 chunks of 16B; global chunk c of row r lives in slot
// c ^ u4(r); reads/writes are <=2-way bank aliased (free).
// EPI_SWIGLU: dual W banks + dual acc -> a*silu(g).
// EPI_DUALX : dual W banks + dual X, single acc (Y = W0@X0 + W1@X1 + bias),
//             plus second output Y2 = bf16T(rms-normalized Y) (H2 epilogue).
template<int EPI, bool RMS, bool XT, typename TY, bool YT, int CFG>
__global__ __launch_bounds__(256, 2) void gemm_k(
    const void* __restrict__ Xv,
    const void* __restrict__ Xv2,
    const unsigned short* __restrict__ W,
    const float* __restrict__ bias,
    TY* Y,
    unsigned short* Y2,
    int Xs, int Xoff, int Ys, int Yoff, int Ys2)
{
  constexpr bool WDUAL = (EPI == EPI_SWIGLU) || (EPI == EPI_DUALX);
  constexpr bool GDUAL = (EPI == EPI_SWIGLU);
  constexpr bool XDUAL = (EPI == EPI_DUALX);
  constexpr bool H2    = (EPI == EPI_DUALX);
  constexpr int NWV = (CFG == 0) ? 1 : 2;       // waves on N
  constexpr int BM  = (CFG == 0) ? 256 : 128;
  constexpr int WN  = 64 / NWV;                 // wave N width
  constexpr int NFR = WN / 16;                  // n-frags per wave
  constexpr int RW  = (WDUAL ? 2 : 1) * BM;     // sA rows
  constexpr int XR  = (XDUAL ? 2 : 1) * 64;     // sX rows

  __shared__ unsigned short sA[RW * 32];
  __shared__ unsigned short sX[XR * 32];
  __shared__ float red[4][64];

  const int tid = threadIdx.x;
  const int lane = tid & 63;
  const int wid = tid >> 6;
  const int l15 = lane & 15;
  const int q4 = lane >> 4;
  const int z = blockIdx.z;
  const int p0 = blockIdx.x * 64;
  const int m0 = blockIdx.y * BM;
  const int mh = (CFG == 0) ? wid : (wid >> 1);
  const int nh = (CFG == 0) ? 0 : (wid & 1);

  const float* Xf = nullptr;
  const unsigned short* Xt = nullptr;
  const unsigned short* Xt2 = nullptr;
  if constexpr (XT) {
    Xt = (const unsigned short*)Xv + ((size_t)z * Xs + Xoff + p0) * C_;
    if constexpr (XDUAL)
      Xt2 = (const unsigned short*)Xv2 + ((size_t)z * Xs + Xoff + p0) * C_;
  } else {
    Xf = (const float*)Xv + (size_t)z * C_ * Xs + Xoff + p0;
  }

  const f32x4 zf = {0.f, 0.f, 0.f, 0.f};
  f32x4 acc0[4][NFR];
  f32x4 acc1[GDUAL ? 4 : 1][NFR];
  #pragma unroll
  for (int i = 0; i < 4; ++i)
    #pragma unroll
    for (int j = 0; j < NFR; ++j) {
      acc0[i][j] = zf;
      if constexpr (GDUAL) acc1[i][j] = zf;
    }

  float sq = 0.f;   // fp32-path per-pixel sumsq partial (pixel = lane)

  for (int kt = 0; kt < 8; ++kt) {
    // ---- stage X ----
    if constexpr (XT) {
      const int row = wid * 16 + (lane >> 2);
      const int chunk = (lane & 3) ^ u4i(row);
      const size_t soff = (size_t)row * C_ + kt * 32 + (chunk << 3);
      gload16(Xt + soff, &sX[(wid * 16) * 32]);
      if constexpr (XDUAL) gload16(Xt2 + soff, &sX[(64 + wid * 16) * 32]);
    } else {
      const float* xp = Xf + (size_t)(kt * 32 + wid * 8) * Xs + lane;
      float v[8];
      #pragma unroll
      for (int j = 0; j < 8; ++j) v[j] = xp[(size_t)j * Xs];
      bf16x8 w8;
      #pragma unroll
      for (int j = 0; j < 8; ++j) {
        if constexpr (RMS) sq = fmaf(v[j], v[j], sq);
        w8[j] = (short)f2b(v[j]);
      }
      *(bf16x8*)((char*)sX + lane * 64 + ((wid ^ u4i(lane)) << 4)) = w8;
    }
    // ---- stage W (global_load_lds, source-swizzled) ----
    #pragma unroll
    for (int it = 0; it < RW / 64; ++it) {
      const int rbase = wid * (RW / 4) + it * 16;
      const int rl = rbase + (lane >> 2);
      const int bank = rl / BM;
      const int rloc = rl & (BM - 1);
      const int chunk = (lane & 3) ^ u4i(rl);
      gload16(W + (size_t)(bank * C_ + m0 + rloc) * C_ + kt * 32 + (chunk << 3),
              &sA[rbase * 32]);
    }
    __syncthreads();

    // ---- fragments + MFMA ----
    bf16x8 af0[4], af1[4], bfr[NFR], bfr2[NFR];
    #pragma unroll
    for (int mf = 0; mf < 4; ++mf) {
      const int r = mh * 64 + mf * 16 + l15;
      const int sl = (q4 ^ u4i(r)) << 3;
      af0[mf] = *(const bf16x8*)(&sA[r * 32 + sl]);
      if constexpr (WDUAL) af1[mf] = *(const bf16x8*)(&sA[(BM + r) * 32 + sl]);
    }
    #pragma unroll
    for (int nf = 0; nf < NFR; ++nf) {
      const int n = nh * WN + nf * 16 + l15;
      const int sl = (q4 ^ u4i(n)) << 3;
      bfr[nf] = *(const bf16x8*)(&sX[n * 32 + sl]);
      if constexpr (XDUAL) bfr2[nf] = *(const bf16x8*)(&sX[(64 + n) * 32 + sl]);
    }
    #pragma unroll
    for (int mf = 0; mf < 4; ++mf)
      #pragma unroll
      for (int nf = 0; nf < NFR; ++nf) {
        acc0[mf][nf] = __builtin_amdgcn_mfma_f32_16x16x32_bf16(af0[mf], bfr[nf], acc0[mf][nf], 0, 0, 0);
        if constexpr (GDUAL)
          acc1[mf][nf] = __builtin_amdgcn_mfma_f32_16x16x32_bf16(af1[mf], bfr[nf], acc1[mf][nf], 0, 0, 0);
        if constexpr (XDUAL)
          acc0[mf][nf] = __builtin_amdgcn_mfma_f32_16x16x32_bf16(af1[mf], bfr2[nf], acc0[mf][nf], 0, 0, 0);
      }
    __syncthreads();
  }

  // ---- fused RMS colscale (fp32 path) ----
  float cs[NFR];
  #pragma unroll
  for (int nf = 0; nf < NFR; ++nf) cs[nf] = 1.f;
  if constexpr (RMS) {
    red[wid][lane] = sq;
    __syncthreads();
    #pragma unroll
    for (int nf = 0; nf < NFR; ++nf) {
      const int n = nh * WN + nf * 16 + l15;
      cs[nf] = rsqrtf((red[0][n] + red[1][n] + red[2][n] + red[3][n]) * (1.0f / (float)C_) + 1e-6f);
    }
  }

  // ---- epilogue ----
  TY* Yb = nullptr;
  if constexpr (!YT) Yb = Y + (size_t)z * C_ * Ys + Yoff;

  float p2[NFR];
  #pragma unroll
  for (int nf = 0; nf < NFR; ++nf) p2[nf] = 0.f;

  #pragma unroll
  for (int mf = 0; mf < 4; ++mf) {
    const int mb = m0 + mh * 64 + mf * 16 + q4 * 4;
    const float4 b1 = *(const float4*)(bias + mb);
    float4 b2 = {0.f, 0.f, 0.f, 0.f};
    if constexpr (GDUAL) b2 = *(const float4*)(bias + C_ + mb);
    #pragma unroll
    for (int nf = 0; nf < NFR; ++nf) {
      const int pl = p0 + nh * WN + nf * 16 + l15;
      if constexpr (YT) {
        bf16x4 pk;
        #pragma unroll
        for (int r = 0; r < 4; ++r) {
          float y = acc0[mf][nf][r] * cs[nf] + ((const float*)&b1)[r];
          if constexpr (EPI == EPI_SILU) y = y / (1.0f + __expf(-y));
          if constexpr (EPI == EPI_SWIGLU) {
            float g = acc1[mf][nf][r] * cs[nf] + ((const float*)&b2)[r];
            y = y * (g / (1.0f + __expf(-g)));
          }
          pk[r] = (short)f2b(y);
        }
        *(bf16x4*)(Y + ((size_t)z * Ys + Yoff + pl) * C_ + mb) = pk;
      } else {
        #pragma unroll
        for (int r = 0; r < 4; ++r) {
          const size_t oidx = (size_t)(mb + r) * Ys + pl;
          float y = acc0[mf][nf][r] * cs[nf] + ((const float*)&b1)[r];
          if constexpr (EPI == EPI_SILU) y = y / (1.0f + __expf(-y));
          if constexpr (EPI == EPI_SWIGLU) {
            float g = acc1[mf][nf][r] * cs[nf] + ((const float*)&b2)[r];
            y = y * (g / (1.0f + __expf(-g)));
          }
          if constexpr (EPI == EPI_RESID) y += ldv(Yb[oidx]);
          if constexpr (H2) p2[nf] = fmaf(y, y, p2[nf]);
          stv(&Yb[oidx], y);
        }
      }
    }
  }

  // ---- H2: second output = bf16T( hidden * rsqrt(mean(hidden^2)) ) ----
  if constexpr (H2) {
    #pragma unroll
    for (int nf = 0; nf < NFR; ++nf) {
      p2[nf] += __shfl_xor(p2[nf], 16);
      p2[nf] += __shfl_xor(p2[nf], 32);
    }
    if (q4 == 0) {
      #pragma unroll
      for (int nf = 0; nf < NFR; ++nf) red[wid][nf * 16 + l15] = p2[nf];
    }
    __syncthreads();
    float cs2[NFR];
    #pragma unroll
    for (int nf = 0; nf < NFR; ++nf) {
      const int n = nf * 16 + l15;
      cs2[nf] = rsqrtf((red[0][n] + red[1][n] + red[2][n] + red[3][n]) * (1.0f / (float)C_) + 1e-6f);
    }
    #pragma unroll
    for (int mf = 0; mf < 4; ++mf) {
      const int mb = m0 + mh * 64 + mf * 16 + q4 * 4;
      const float4 b1 = *(const float4*)(bias + mb);
      #pragma unroll
      for (int nf = 0; nf < NFR; ++nf) {
        const int pl = p0 + nf * 16 + l15;
        bf16x4 pk;
        #pragma unroll
        for (int r = 0; r < 4; ++r) {
          const float h = (acc0[mf][nf][r] + ((const float*)&b1)[r]) * cs2[nf];
          pk[r] = (short)f2b(h);
        }
        *(bf16x4*)(Y2 + ((size_t)z * Ys2 + pl) * C_ + mb) = pk;
      }
    }
  }
}

// -------------------------------------------------------------------------
// Fused cross-attention, one block per (z, t_local).
// Q, K transposed bf16 [pix][C_]; V non-transposed [C_][pix]; O transposed (in-place on Q buf).
// sK/sQ: linear [64][256] with 8-way chunk XOR: slot s of row n holds chunk s ^ (n&7).
__global__ __launch_bounds__(256) void attn_k(
    const unsigned short* Q,
    const unsigned short* __restrict__ Kp,
    const unsigned short* __restrict__ Vp,
    const float* __restrict__ basis,
    const float* __restrict__ ssp,
    const float* __restrict__ psp,
    unsigned short* O,
    int PsQ, int t0, int ltc)
{
  __shared__ unsigned short sK[64 * 256];
  __shared__ unsigned short sQ[64 * 256];
  __shared__ unsigned short sV[256 * 72];   // [c][n] (A-operand)
  __shared__ unsigned short sW[64 * 72];    // [f][n] softmax weights (B-operand)
  __shared__ unsigned short sB[64 * 72];    // [n][f] bias chunk

  const int tid = threadIdx.x;
  const int lane = tid & 63;
  const int wid = tid >> 6;
  const int l15 = lane & 15;
  const int q4 = lane >> 4;
  const int z = blockIdx.x >> ltc;
  const int tl = blockIdx.x & ((1 << ltc) - 1);

  const unsigned short* Qt = Q + ((size_t)z * PsQ + (size_t)tl * NF_) * C_;
  unsigned short*       Ot = O + ((size_t)z * PsQ + (size_t)tl * NF_) * C_;
  const unsigned short* Kt = Kp + ((size_t)z * PLAT_ + (size_t)(t0 + tl) * NB_) * C_;
  const size_t vbase = (size_t)z * C_ * PLAT_ + (size_t)(t0 + tl) * NB_;

  const float ss = ssp[0];
  const float ps = psp[0];
  const f32x4 zf = {0.f, 0.f, 0.f, 0.f};

  // stage K (gload_lds, swizzled) and V (reg path) once per block
  {
    #pragma unroll
    for (int it = 0; it < 8; ++it) {
      int i = wid * 8 + it;
      int n = 2 * i + (lane >> 5);
      int sc = (lane & 31) ^ (n & 7);
      gload16(Kt + (size_t)n * C_ + (sc << 3), &sK[i * 512]);
    }
    const int c0 = tid >> 3;
    const int n0 = (tid & 7) << 3;
    #pragma unroll
    for (int pass = 0; pass < 8; ++pass) {
      int c = c0 + pass * 32;
      bf16x8 v8 = *(const bf16x8*)(Vp + vbase + (size_t)c * PLAT_ + n0);
      *(bf16x8*)(&sV[c * 72 + n0]) = v8;
    }
  }

  for (int fc = 0; fc < 8; ++fc) {
    const int f0 = fc * 64;
    // stage Q chunk (gload_lds, swizzled) and fp32 bias chunk [n][f]
    #pragma unroll
    for (int it = 0; it < 8; ++it) {
      int i = wid * 8 + it;
      int n = 2 * i + (lane >> 5);
      int sc = (lane & 31) ^ (n & 7);
      gload16(Qt + (size_t)(f0 + n) * C_ + (sc << 3), &sQ[i * 512]);
    }
    {
      const int nr = tid >> 3;
      const int fl0 = (tid & 7) << 3;
      #pragma unroll
      for (int pass = 0; pass < 2; ++pass) {
        int nn = nr + pass * 32;
        bf16x8 b8 = ld8(basis + (size_t)nn * NF_ + f0 + fl0);
        *(bf16x8*)(&sB[nn * 72 + fl0]) = b8;
      }
    }
    __syncthreads();

    // scores: wave wid owns f rows [wid*16, wid*16+16)
    f32x4 sacc[4];
    #pragma unroll
    for (int nt = 0; nt < 4; ++nt) sacc[nt] = zf;
    const int frow = wid * 16 + l15;
    const int swq = l15 & 7;
    #pragma unroll
    for (int kt = 0; kt < 8; ++kt) {
      int kb = kt * 4 + q4;
      bf16x8 a8 = *(const bf16x8*)(&sQ[frow * 256 + ((kb ^ swq) << 3)]);
      #pragma unroll
      for (int nt = 0; nt < 4; ++nt) {
        bf16x8 b8 = *(const bf16x8*)(&sK[(nt * 16 + l15) * 256 + ((kb ^ swq) << 3)]);
        sacc[nt] = __builtin_amdgcn_mfma_f32_16x16x32_bf16(a8, b8, sacc[nt], 0, 0, 0);
      }
    }

    // softmax over n=64
    #pragma unroll
    for (int r = 0; r < 4; ++r) {
      const int fcl = wid * 16 + q4 * 4 + r;
      float v[4];
      #pragma unroll
      for (int nt = 0; nt < 4; ++nt)
        v[nt] = sacc[nt][r] * ss + b2f(sB[(nt * 16 + l15) * 72 + fcl]) * ps;
      float mx = fmaxf(fmaxf(v[0], v[1]), fmaxf(v[2], v[3]));
      #pragma unroll
      for (int d = 1; d < 16; d <<= 1) mx = fmaxf(mx, __shfl_xor(mx, d));
      float e[4], sum = 0.f;
      #pragma unroll
      for (int nt = 0; nt < 4; ++nt) { e[nt] = __expf(v[nt] - mx); sum += e[nt]; }
      #pragma unroll
      for (int d = 1; d < 16; d <<= 1) sum += __shfl_xor(sum, d);
      float inv = 1.0f / sum;
      #pragma unroll
      for (int nt = 0; nt < 4; ++nt)
        sW[fcl * 72 + nt * 16 + l15] = f2b(e[nt] * inv);
    }
    __syncthreads();

    // PV: wave wid owns c rows [wid*64, wid*64+64)
    f32x4 pacc[4][4];
    #pragma unroll
    for (int mf = 0; mf < 4; ++mf)
      #pragma unroll
      for (int nf = 0; nf < 4; ++nf) pacc[mf][nf] = zf;
    #pragma unroll
    for (int kt = 0; kt < 2; ++kt) {
      int k0 = kt * 32 + q4 * 8;
      bf16x8 a8[4], b8[4];
      #pragma unroll
      for (int mf = 0; mf < 4; ++mf)
        a8[mf] = *(const bf16x8*)(&sV[(wid * 64 + mf * 16 + l15) * 72 + k0]);
      #pragma unroll
      for (int nf = 0; nf < 4; ++nf)
        b8[nf] = *(const bf16x8*)(&sW[(nf * 16 + l15) * 72 + k0]);
      #pragma unroll
      for (int mf = 0; mf < 4; ++mf)
        #pragma unroll
        for (int nf = 0; nf < 4; ++nf)
          pacc[mf][nf] = __builtin_amdgcn_mfma_f32_16x16x32_bf16(a8[mf], b8[nf], pacc[mf][nf], 0, 0, 0);
    }
    // O write, transposed [f][c], 8B per store
    #pragma unroll
    for (int mf = 0; mf < 4; ++mf) {
      int cb = wid * 64 + mf * 16 + q4 * 4;
      #pragma unroll
      for (int nf = 0; nf < 4; ++nf) {
        int f = f0 + nf * 16 + l15;
        bf16x4 pk;
        #pragma unroll
        for (int r = 0; r < 4; ++r) pk[r] = (short)f2b(pacc[mf][nf][r]);
        *(bf16x4*)(Ot + (size_t)f * C_ + cb) = pk;
      }
    }
    __syncthreads();
  }
}

// -------------------------------------------------------------------------
extern "C" void kernel_launch(void* const* d_in, const int* in_sizes, int n_in,
                              void* d_out, int out_size, void* d_ws, size_t ws_size,
                              hipStream_t stream)
{
  (void)in_sizes; (void)n_in; (void)out_size;
  const float* latent     = (const float*)d_in[0];
  const float* side       = (const float*)d_in[1];
  const float* basis      = (const float*)d_in[2];
  const float* lp_norm_w  = (const float*)d_in[3];
  const float* lp_w       = (const float*)d_in[4];
  const float* lp_b       = (const float*)d_in[5];
  const float* qn_w       = (const float*)d_in[6];
  const float* qmlp_in_w  = (const float*)d_in[7];
  const float* qmlp_in_b  = (const float*)d_in[8];
  const float* qmlp_out_w = (const float*)d_in[9];
  const float* qmlp_out_b = (const float*)d_in[10];
  const float* q_w        = (const float*)d_in[11];
  const float* q_b        = (const float*)d_in[12];
  const float* k_w        = (const float*)d_in[13];
  const float* k_b        = (const float*)d_in[14];
  const float* v_w        = (const float*)d_in[15];
  const float* v_b        = (const float*)d_in[16];
  const float* o_w        = (const float*)d_in[17];
  const float* o_b        = (const float*)d_in[18];
  const float* ffn_norm_w = (const float*)d_in[19];
  const float* ffn_in_w   = (const float*)d_in[20];
  const float* ffn_in_b   = (const float*)d_in[21];
  const float* ffn_out_w  = (const float*)d_in[22];
  const float* ffn_out_b  = (const float*)d_in[23];
  const float* sc_scale   = (const float*)d_in[24];
  const float* pr_scale   = (const float*)d_in[25];
  const float* qk_scale   = (const float*)d_in[26];
  float* out = (float*)d_out;

  // ---- workspace carve, chunk count chosen to FIT ws_size ----
  // fixed part: 5x (C*C bf16) + 3x (2C*C bf16) + 2x (C fp32) + 3x (B*C*PLAT bf16)
  auto align256 = [](size_t b) { return (b + 255) & ~(size_t)255; };
  const size_t fixed_bytes =
      5 * align256((size_t)C_ * C_ * 2) +
      3 * align256((size_t)2 * C_ * C_ * 2) +
      2 * align256((size_t)C_ * 4) +
      3 * align256((size_t)B_ * C_ * PLAT_ * 2);
  int nc = 16;
  for (int c = 1; c <= 16; c <<= 1) {
    size_t Pcb = (size_t)PSIDE_ / c;
    size_t need = fixed_bytes + 2 * align256((size_t)B_ * C_ * Pcb * 2);
    if (need <= ws_size) { nc = c; break; }
  }
  const int Pc  = PSIDE_ / nc;
  const int Tc  = T_ / nc;
  int ltc = 0; while ((1 << ltc) < Tc) ++ltc;   // log2(Tc)

  char* ws = (char*)d_ws;
  size_t off = 0;
  auto carve = [&](size_t bytes) -> char* {
    char* p = ws + off;
    off += (bytes + 255) & ~(size_t)255;
    return p;
  };
  unsigned short* wlp      = (unsigned short*)carve((size_t)C_ * C_ * 2);
  unsigned short* wqin     = (unsigned short*)carve((size_t)2 * C_ * C_ * 2);
  unsigned short* wffin    = (unsigned short*)carve((size_t)2 * C_ * C_ * 2);
  unsigned short* wk       = (unsigned short*)carve((size_t)C_ * C_ * 2);
  unsigned short* wv       = (unsigned short*)carve((size_t)C_ * C_ * 2);
  unsigned short* wfo      = (unsigned short*)carve((size_t)C_ * C_ * 2);
  unsigned short* wqeff    = (unsigned short*)carve((size_t)C_ * C_ * 2);
  unsigned short* wocat    = (unsigned short*)carve((size_t)2 * C_ * C_ * 2);  // [o_w ; qss*qmlp_out_w]
  float*          beff     = (float*)carve((size_t)C_ * 4);
  float*          bcomb    = (float*)carve((size_t)C_ * 4);
  unsigned short* latent_h = (unsigned short*)carve((size_t)B_ * C_ * PLAT_ * 2);
  unsigned short* kbuf     = (unsigned short*)carve((size_t)B_ * C_ * PLAT_ * 2);
  unsigned short* vbuf     = (unsigned short*)carve((size_t)B_ * C_ * PLAT_ * 2);
  unsigned short* big0     = (unsigned short*)carve((size_t)B_ * C_ * Pc * 2);
  unsigned short* qbuf     = (unsigned short*)carve((size_t)B_ * C_ * Pc * 2);

  const dim3 blk(256);
  const dim3 gLatA(PLAT_ / 64, 1, B_);
  const dim3 gChA(Pc / 64, 1, B_);
  const dim3 gChB(Pc / 64, 2, B_);
  const int NW = C_ * C_;   // 65536

  // weight prep
  wprep_k<<<dim3(NW / 256), blk, 0, stream>>>(lp_w, lp_norm_w, wlp, NW);
  wprep_k<<<dim3(2 * NW / 256), blk, 0, stream>>>(qmlp_in_w, qn_w, wqin, 2 * NW);
  wprep_k<<<dim3(2 * NW / 256), blk, 0, stream>>>(ffn_in_w, ffn_norm_w, wffin, 2 * NW);
  cvt_k<<<dim3(NW / 256), blk, 0, stream>>>(k_w, wk, NW);
  cvt_k<<<dim3(NW / 256), blk, 0, stream>>>(v_w, wv, NW);
  cvt_k<<<dim3(NW / 256), blk, 0, stream>>>(ffn_out_w, wfo, NW);
  foldw_k<<<dim3(C_), blk, 0, stream>>>(q_w, qmlp_out_w, wqeff);
  foldb_k<<<dim3(1), blk, 0, stream>>>(q_w, qmlp_out_b, q_b, beff);
  cvt_k<<<dim3(NW / 256), blk, 0, stream>>>(o_w, wocat, NW);
  wscale_k<<<dim3(NW / 256), blk, 0, stream>>>(qmlp_out_w, qk_scale, wocat + (size_t)NW, NW);
  bcomb_k<<<dim3(1), blk, 0, stream>>>(o_b, qmlp_out_b, qk_scale, bcomb);

  // latent path (once): rms fused into lp-gemm
  gemm_k<EPI_SILU, true, false, unsigned short, true, 0><<<gLatA, blk, 0, stream>>>(
      latent, nullptr, wlp, lp_b, latent_h, nullptr, PLAT_, 0, PLAT_, 0, 0);
  gemm_k<EPI_NONE, false, true, unsigned short, true, 0><<<gLatA, blk, 0, stream>>>(
      latent_h, nullptr, wk, k_b, kbuf, nullptr, PLAT_, 0, PLAT_, 0, 0);
  gemm_k<EPI_NONE, false, true, unsigned short, false, 0><<<gLatA, blk, 0, stream>>>(
      latent_h, nullptr, wv, v_b, vbuf, nullptr, PLAT_, 0, PLAT_, 0, 0);

  // side path, chunked over t
  for (int ch = 0; ch < nc; ++ch) {
    const int co = ch * Pc;
    const int t0 = ch * Tc;
    // big0 = swiglu_inner(qmlp_in @ rms(side))   [rms fused]
    gemm_k<EPI_SWIGLU, true, false, unsigned short, true, 1><<<gChB, blk, 0, stream>>>(
        side, nullptr, wqin, qmlp_in_b, big0, nullptr, PSIDE_, co, Pc, 0, 0);
    // qbuf = (q_w @ qmlp_out) @ big0 + folded bias
    gemm_k<EPI_NONE, false, true, unsigned short, true, 0><<<gChA, blk, 0, stream>>>(
        big0, nullptr, wqeff, beff, qbuf, nullptr, Pc, 0, Pc, 0, 0);
    // attention in-place over qbuf
    attn_k<<<dim3(B_ * Tc), blk, 0, stream>>>(qbuf, kbuf, vbuf, basis, sc_scale, pr_scale,
                                              qbuf, Pc, t0, ltc);
    // out = o_w @ attended + qss*(qmlp_out @ big0) + comb_bias
    // also: qbuf <- bf16T( rms-normalized hidden )   (in-place, same rows)
    gemm_k<EPI_DUALX, false, true, float, false, 0><<<gChA, blk, 0, stream>>>(
        qbuf, big0, wocat, bcomb, out, qbuf, Pc, 0, PSIDE_, co, Pc);
    // FFN in: reads pre-normalized hiddenT (norm-w folded into wffin)
    gemm_k<EPI_SWIGLU, false, true, unsigned short, true, 1><<<gChB, blk, 0, stream>>>(
        qbuf, nullptr, wffin, ffn_in_b, big0, nullptr, Pc, 0, Pc, 0, 0);
    gemm_k<EPI_RESID, false, true, float, false, 0><<<gChA, blk, 0, stream>>>(
        big0, nullptr, wfo, ffn_out_b, out, nullptr, Pc, 0, PSIDE_, co, 0);
  }
}

// Round 5
// 1284.856 us; speedup vs baseline: 1.4412x; 1.1339x over previous
//
#include <hip/hip_runtime.h>
#include <stdint.h>
#include <stddef.h>

#define B_ 4
#define C_ 256
#define T_ 128
#define NB_ 64
#define NF_ 512
#define PLAT_ (T_*NB_)    // 8192
#define PSIDE_ (T_*NF_)   // 65536

using bf16x8 = __attribute__((ext_vector_type(8))) short;
using bf16x4 = __attribute__((ext_vector_type(4))) short;
using f32x4  = __attribute__((ext_vector_type(4))) float;

__device__ __forceinline__ float b2f(unsigned short h) {
  unsigned int u = ((unsigned int)h) << 16;
  return __builtin_bit_cast(float, u);
}
__device__ __forceinline__ float b2f(short h) {
  unsigned int u = ((unsigned int)(unsigned short)h) << 16;
  return __builtin_bit_cast(float, u);
}
__device__ __forceinline__ unsigned short f2b(float f) {
  unsigned int u = __builtin_bit_cast(unsigned int, f);
  u += 0x7FFFu + ((u >> 16) & 1u);
  return (unsigned short)(u >> 16);
}

__device__ __forceinline__ bf16x8 ld8(const unsigned short* p) {
  return *(const bf16x8*)p;
}
__device__ __forceinline__ bf16x8 ld8(const float* p) {
  float4 a = *(const float4*)p;
  float4 b = *(const float4*)(p + 4);
  bf16x8 r;
  r[0] = (short)f2b(a.x); r[1] = (short)f2b(a.y);
  r[2] = (short)f2b(a.z); r[3] = (short)f2b(a.w);
  r[4] = (short)f2b(b.x); r[5] = (short)f2b(b.y);
  r[6] = (short)f2b(b.z); r[7] = (short)f2b(b.w);
  return r;
}
__device__ __forceinline__ void stv(float* p, float v) { *p = v; }
__device__ __forceinline__ void stv(unsigned short* p, float v) { *p = f2b(v); }

// async global->LDS, 16B per lane; lds dst must be wave-uniform base (lane*16 added by HW)
__device__ __forceinline__ void gload16(const void* g, void* l) {
  __builtin_amdgcn_global_load_lds(
      (const __attribute__((address_space(1))) void*)g,
      (__attribute__((address_space(3))) void*)l, 16, 0, 0);
}

// chunk-XOR swizzle selector for 4x16B rows; u4i(r + 128k) == u4i(r)
__device__ __forceinline__ int u4i(int r) { return (r ^ (r >> 2)) & 3; }

enum { EPI_NONE = 0, EPI_SILU = 1, EPI_RESID = 3, EPI_SWIGLU = 4, EPI_DUALX = 5 };

// fold per-channel norm weight into conv weight (fp32 in, bf16 out)
__global__ __launch_bounds__(256) void wprep_k(const float* __restrict__ w,
                                               const float* __restrict__ nw,
                                               unsigned short* __restrict__ out, int n)
{
  int i = blockIdx.x * 256 + threadIdx.x;
  if (i < n) out[i] = f2b(w[i] * nw[i & 255]);
}

// plain fp32 -> bf16 convert
__global__ __launch_bounds__(256) void cvt_k(const float* __restrict__ in,
                                             unsigned short* __restrict__ out, int n)
{
  int i = blockIdx.x * 256 + threadIdx.x;
  if (i < n) out[i] = f2b(in[i]);
}

// scaled convert: out[i] = bf16(w[i] * s[0])
__global__ __launch_bounds__(256) void wscale_k(const float* __restrict__ w,
                                                const float* __restrict__ s,
                                                unsigned short* __restrict__ out, int n)
{
  int i = blockIdx.x * 256 + threadIdx.x;
  if (i < n) out[i] = f2b(w[i] * s[0]);
}

// weight fold: out[m][c] = bf16( sum_j A[m][j] * Bm[j][c] )  (q_w @ qmlp_out)
__global__ __launch_bounds__(256) void foldw_k(const float* __restrict__ A,
                                               const float* __restrict__ Bm,
                                               unsigned short* __restrict__ out)
{
  const int m = blockIdx.x;
  const int c = threadIdx.x;
  float acc = 0.f;
  #pragma unroll 8
  for (int j = 0; j < C_; ++j) acc = fmaf(A[m * C_ + j], Bm[j * C_ + c], acc);
  out[m * C_ + c] = f2b(acc);
}

// bias fold: bout[m] = sum_j A[m][j]*bin[j] + badd[m]
__global__ __launch_bounds__(256) void foldb_k(const float* __restrict__ A,
                                               const float* __restrict__ bin,
                                               const float* __restrict__ badd,
                                               float* __restrict__ bout)
{
  const int m = threadIdx.x;
  float acc = 0.f;
  #pragma unroll 8
  for (int j = 0; j < C_; ++j) acc = fmaf(A[m * C_ + j], bin[j], acc);
  bout[m] = acc + badd[m];
}

// bias combine: bout[m] = b0[m] + s[0]*b1[m]
__global__ __launch_bounds__(256) void bcomb_k(const float* __restrict__ b0,
                                               const float* __restrict__ b1,
                                               const float* __restrict__ s,
                                               float* __restrict__ bout)
{
  const int m = threadIdx.x;
  bout[m] = b0[m] + s[0] * b1[m];
}

// -------------------------------------------------------------------------
// GEMM over channels, tall-M blocks (no m-redundancy on X reads).
// CFG 0: BM=256, grid.x = strips, 4 waves on M, BN=64 (wave tile 64x64).
// CFG 1: BM=128, grid.x = 2*strips (paired: y = bx&1 so both W-halves of one
//        strip are dispatch-adjacent -> X strip L2-hits), 2x2 waves.
// X layouts:
//  XT=true : X bf16 transposed [z][pix][C_] -> global_load_lds, source-swizzled
//  XT=false: X fp32 [z][C_][Xs] -> k-major per-thread loads, pack bf16x8,
//            one ds_write_b128. RMS fused via per-pixel sumsq.
// EPI_SWIGLU: dual W banks + dual acc -> a*silu(g); optional CSIN col-scale.
// EPI_DUALX : dual W banks + dual X, single acc; writes hidden bf16T (YT) and
//             per-pixel RMS scale to pscale (norm deferred to consumer).
// EPI_RESID : Y = acc + bias + bf16T-residual RT (final fp32 out, no RMW).
template<int EPI, bool RMS, bool XT, typename TY, bool YT, int CFG, bool CSIN>
__global__ __launch_bounds__(256, 2) void gemm_k(
    const void* __restrict__ Xv,
    const void* __restrict__ Xv2,
    const unsigned short* __restrict__ W,
    const float* __restrict__ bias,
    TY* Y,
    const unsigned short* __restrict__ RT,
    float* pscale,
    int Xs, int Xoff, int Ys, int Yoff, int Ps)
{
  constexpr bool WDUAL = (EPI == EPI_SWIGLU) || (EPI == EPI_DUALX);
  constexpr bool GDUAL = (EPI == EPI_SWIGLU);
  constexpr bool XDUAL = (EPI == EPI_DUALX);
  constexpr int BM  = (CFG == 0) ? 256 : 128;
  constexpr int NWV = (CFG == 0) ? 1 : 2;       // waves on N
  constexpr int WN  = 64 / NWV;                 // wave N width
  constexpr int NFR = WN / 16;                  // n-frags per wave
  constexpr int RW  = (WDUAL ? 2 : 1) * BM;     // sA rows
  constexpr int XR  = (XDUAL ? 2 : 1) * 64;     // sX rows

  __shared__ unsigned short sA[RW * 32];
  __shared__ unsigned short sX[XR * 32];
  __shared__ float red[4][64];

  const int tid = threadIdx.x;
  const int lane = tid & 63;
  const int wid = tid >> 6;
  const int l15 = lane & 15;
  const int q4 = lane >> 4;
  const int z = blockIdx.z;
  const int p0 = ((CFG == 0) ? blockIdx.x : (blockIdx.x >> 1)) * 64;
  const int m0 = (CFG == 0) ? 0 : (blockIdx.x & 1) * BM;
  const int mh = (CFG == 0) ? wid : (wid >> 1);
  const int nh = (CFG == 0) ? 0 : (wid & 1);

  const float* Xf = nullptr;
  const unsigned short* Xt = nullptr;
  const unsigned short* Xt2 = nullptr;
  if constexpr (XT) {
    Xt = (const unsigned short*)Xv + ((size_t)z * Xs + Xoff + p0) * C_;
    if constexpr (XDUAL)
      Xt2 = (const unsigned short*)Xv2 + ((size_t)z * Xs + Xoff + p0) * C_;
  } else {
    Xf = (const float*)Xv + (size_t)z * C_ * Xs + Xoff + p0;
  }

  const f32x4 zf = {0.f, 0.f, 0.f, 0.f};
  f32x4 acc0[4][NFR];
  f32x4 acc1[GDUAL ? 4 : 1][NFR];
  #pragma unroll
  for (int i = 0; i < 4; ++i)
    #pragma unroll
    for (int j = 0; j < NFR; ++j) {
      acc0[i][j] = zf;
      if constexpr (GDUAL) acc1[i][j] = zf;
    }

  float sq = 0.f;   // fp32-path per-pixel sumsq partial (pixel = lane)

  for (int kt = 0; kt < 8; ++kt) {
    // ---- stage X ----
    if constexpr (XT) {
      const int row = wid * 16 + (lane >> 2);
      const int chunk = (lane & 3) ^ u4i(row);
      const size_t soff = (size_t)row * C_ + kt * 32 + (chunk << 3);
      gload16(Xt + soff, &sX[(wid * 16) * 32]);
      if constexpr (XDUAL) gload16(Xt2 + soff, &sX[(64 + wid * 16) * 32]);
    } else {
      const float* xp = Xf + (size_t)(kt * 32 + wid * 8) * Xs + lane;
      float v[8];
      #pragma unroll
      for (int j = 0; j < 8; ++j) v[j] = xp[(size_t)j * Xs];
      bf16x8 w8;
      #pragma unroll
      for (int j = 0; j < 8; ++j) {
        if constexpr (RMS) sq = fmaf(v[j], v[j], sq);
        w8[j] = (short)f2b(v[j]);
      }
      *(bf16x8*)((char*)sX + lane * 64 + ((wid ^ u4i(lane)) << 4)) = w8;
    }
    // ---- stage W (global_load_lds, source-swizzled) ----
    #pragma unroll
    for (int it = 0; it < RW / 64; ++it) {
      const int rbase = wid * (RW / 4) + it * 16;
      const int rl = rbase + (lane >> 2);
      const int bank = rl / BM;
      const int rloc = rl & (BM - 1);
      const int chunk = (lane & 3) ^ u4i(rl);
      gload16(W + (size_t)(bank * C_ + m0 + rloc) * C_ + kt * 32 + (chunk << 3),
              &sA[rbase * 32]);
    }
    __syncthreads();

    // ---- fragments + MFMA ----
    bf16x8 af0[4], af1[4], bfr[NFR], bfr2[NFR];
    #pragma unroll
    for (int mf = 0; mf < 4; ++mf) {
      const int r = mh * 64 + mf * 16 + l15;
      const int sl = (q4 ^ u4i(r)) << 3;
      af0[mf] = *(const bf16x8*)(&sA[r * 32 + sl]);
      if constexpr (WDUAL) af1[mf] = *(const bf16x8*)(&sA[(BM + r) * 32 + sl]);
    }
    #pragma unroll
    for (int nf = 0; nf < NFR; ++nf) {
      const int n = nh * WN + nf * 16 + l15;
      const int sl = (q4 ^ u4i(n)) << 3;
      bfr[nf] = *(const bf16x8*)(&sX[n * 32 + sl]);
      if constexpr (XDUAL) bfr2[nf] = *(const bf16x8*)(&sX[(64 + n) * 32 + sl]);
    }
    #pragma unroll
    for (int mf = 0; mf < 4; ++mf)
      #pragma unroll
      for (int nf = 0; nf < NFR; ++nf) {
        acc0[mf][nf] = __builtin_amdgcn_mfma_f32_16x16x32_bf16(af0[mf], bfr[nf], acc0[mf][nf], 0, 0, 0);
        if constexpr (GDUAL)
          acc1[mf][nf] = __builtin_amdgcn_mfma_f32_16x16x32_bf16(af1[mf], bfr[nf], acc1[mf][nf], 0, 0, 0);
        if constexpr (XDUAL)
          acc0[mf][nf] = __builtin_amdgcn_mfma_f32_16x16x32_bf16(af1[mf], bfr2[nf], acc0[mf][nf], 0, 0, 0);
      }
    __syncthreads();
  }

  // ---- column scales ----
  float cs[NFR];
  #pragma unroll
  for (int nf = 0; nf < NFR; ++nf) cs[nf] = 1.f;
  if constexpr (RMS) {
    red[wid][lane] = sq;
    __syncthreads();
    #pragma unroll
    for (int nf = 0; nf < NFR; ++nf) {
      const int n = nh * WN + nf * 16 + l15;
      cs[nf] = rsqrtf((red[0][n] + red[1][n] + red[2][n] + red[3][n]) * (1.0f / (float)C_) + 1e-6f);
    }
  }
  if constexpr (CSIN) {
    #pragma unroll
    for (int nf = 0; nf < NFR; ++nf)
      cs[nf] = pscale[(size_t)z * Ps + p0 + nh * WN + nf * 16 + l15];
  }

  // ---- epilogue ----
  TY* Yb = nullptr;
  if constexpr (!YT) Yb = Y + (size_t)z * C_ * Ys + Yoff;

  float p2[NFR];
  #pragma unroll
  for (int nf = 0; nf < NFR; ++nf) p2[nf] = 0.f;

  #pragma unroll
  for (int mf = 0; mf < 4; ++mf) {
    const int mb = m0 + mh * 64 + mf * 16 + q4 * 4;
    const float4 b1 = *(const float4*)(bias + mb);
    float4 b2 = {0.f, 0.f, 0.f, 0.f};
    if constexpr (GDUAL) b2 = *(const float4*)(bias + C_ + mb);
    #pragma unroll
    for (int nf = 0; nf < NFR; ++nf) {
      const int pl = p0 + nh * WN + nf * 16 + l15;
      bf16x4 h4 = {0, 0, 0, 0};
      if constexpr (EPI == EPI_RESID)
        h4 = *(const bf16x4*)(RT + ((size_t)z * Ps + pl) * C_ + mb);
      if constexpr (YT) {
        bf16x4 pk;
        #pragma unroll
        for (int r = 0; r < 4; ++r) {
          float y = acc0[mf][nf][r] * cs[nf] + ((const float*)&b1)[r];
          if constexpr (EPI == EPI_SILU) y = y / (1.0f + __expf(-y));
          if constexpr (EPI == EPI_SWIGLU) {
            float g = acc1[mf][nf][r] * cs[nf] + ((const float*)&b2)[r];
            y = y * (g / (1.0f + __expf(-g)));
          }
          if constexpr (EPI == EPI_DUALX) p2[nf] = fmaf(y, y, p2[nf]);
          pk[r] = (short)f2b(y);
        }
        *(bf16x4*)(Y + ((size_t)z * Ys + Yoff + pl) * C_ + mb) = pk;
      } else {
        #pragma unroll
        for (int r = 0; r < 4; ++r) {
          const size_t oidx = (size_t)(mb + r) * Ys + pl;
          float y = acc0[mf][nf][r] * cs[nf] + ((const float*)&b1)[r];
          if constexpr (EPI == EPI_SILU) y = y / (1.0f + __expf(-y));
          if constexpr (EPI == EPI_SWIGLU) {
            float g = acc1[mf][nf][r] * cs[nf] + ((const float*)&b2)[r];
            y = y * (g / (1.0f + __expf(-g)));
          }
          if constexpr (EPI == EPI_RESID) y += b2f(h4[r]);
          stv(&Yb[oidx], y);
        }
      }
    }
  }

  // ---- DUALX tail: per-pixel RMS scale of hidden -> pscale ----
  if constexpr (EPI == EPI_DUALX) {
    #pragma unroll
    for (int nf = 0; nf < NFR; ++nf) {
      p2[nf] += __shfl_xor(p2[nf], 16);
      p2[nf] += __shfl_xor(p2[nf], 32);
    }
    if (q4 == 0) {
      #pragma unroll
      for (int nf = 0; nf < NFR; ++nf) red[wid][nf * 16 + l15] = p2[nf];
    }
    __syncthreads();
    if (wid == 0 && q4 == 0) {
      #pragma unroll
      for (int nf = 0; nf < NFR; ++nf) {
        const int n = nf * 16 + l15;
        const float c2 = rsqrtf((red[0][n] + red[1][n] + red[2][n] + red[3][n]) * (1.0f / (float)C_) + 1e-6f);
        pscale[(size_t)z * Ps + p0 + n] = c2;
      }
    }
  }
}

// -------------------------------------------------------------------------
// Fused cross-attention, one block per (z, t_local).
// Q, K transposed bf16 [pix][C_]; V non-transposed [C_][pix]; O transposed (in-place on Q buf).
// sK/sQ: linear [64][256] with 8-way chunk XOR: slot s of row n holds chunk s ^ (n&7).
__global__ __launch_bounds__(256) void attn_k(
    const unsigned short* Q,
    const unsigned short* __restrict__ Kp,
    const unsigned short* __restrict__ Vp,
    const float* __restrict__ basis,
    const float* __restrict__ ssp,
    const float* __restrict__ psp,
    unsigned short* O,
    int PsQ, int t0, int ltc)
{
  __shared__ unsigned short sK[64 * 256];
  __shared__ unsigned short sQ[64 * 256];
  __shared__ unsigned short sV[256 * 72];   // [c][n] (A-operand)
  __shared__ unsigned short sW[64 * 72];    // [f][n] softmax weights (B-operand)
  __shared__ unsigned short sB[64 * 72];    // [n][f] bias chunk

  const int tid = threadIdx.x;
  const int lane = tid & 63;
  const int wid = tid >> 6;
  const int l15 = lane & 15;
  const int q4 = lane >> 4;
  const int z = blockIdx.x >> ltc;
  const int tl = blockIdx.x & ((1 << ltc) - 1);

  const unsigned short* Qt = Q + ((size_t)z * PsQ + (size_t)tl * NF_) * C_;
  unsigned short*       Ot = O + ((size_t)z * PsQ + (size_t)tl * NF_) * C_;
  const unsigned short* Kt = Kp + ((size_t)z * PLAT_ + (size_t)(t0 + tl) * NB_) * C_;
  const size_t vbase = (size_t)z * C_ * PLAT_ + (size_t)(t0 + tl) * NB_;

  const float ss = ssp[0];
  const float ps = psp[0];
  const f32x4 zf = {0.f, 0.f, 0.f, 0.f};

  // stage K (gload_lds, swizzled) and V (reg path) once per block
  {
    #pragma unroll
    for (int it = 0; it < 8; ++it) {
      int i = wid * 8 + it;
      int n = 2 * i + (lane >> 5);
      int sc = (lane & 31) ^ (n & 7);
      gload16(Kt + (size_t)n * C_ + (sc << 3), &sK[i * 512]);
    }
    const int c0 = tid >> 3;
    const int n0 = (tid & 7) << 3;
    #pragma unroll
    for (int pass = 0; pass < 8; ++pass) {
      int c = c0 + pass * 32;
      bf16x8 v8 = *(const bf16x8*)(Vp + vbase + (size_t)c * PLAT_ + n0);
      *(bf16x8*)(&sV[c * 72 + n0]) = v8;
    }
  }

  for (int fc = 0; fc < 8; ++fc) {
    const int f0 = fc * 64;
    // stage Q chunk (gload_lds, swizzled) and fp32 bias chunk [n][f]
    #pragma unroll
    for (int it = 0; it < 8; ++it) {
      int i = wid * 8 + it;
      int n = 2 * i + (lane >> 5);
      int sc = (lane & 31) ^ (n & 7);
      gload16(Qt + (size_t)(f0 + n) * C_ + (sc << 3), &sQ[i * 512]);
    }
    {
      const int nr = tid >> 3;
      const int fl0 = (tid & 7) << 3;
      #pragma unroll
      for (int pass = 0; pass < 2; ++pass) {
        int nn = nr + pass * 32;
        bf16x8 b8 = ld8(basis + (size_t)nn * NF_ + f0 + fl0);
        *(bf16x8*)(&sB[nn * 72 + fl0]) = b8;
      }
    }
    __syncthreads();

    // scores: wave wid owns f rows [wid*16, wid*16+16)
    f32x4 sacc[4];
    #pragma unroll
    for (int nt = 0; nt < 4; ++nt) sacc[nt] = zf;
    const int frow = wid * 16 + l15;
    const int swq = l15 & 7;
    #pragma unroll
    for (int kt = 0; kt < 8; ++kt) {
      int kb = kt * 4 + q4;
      bf16x8 a8 = *(const bf16x8*)(&sQ[frow * 256 + ((kb ^ swq) << 3)]);
      #pragma unroll
      for (int nt = 0; nt < 4; ++nt) {
        bf16x8 b8 = *(const bf16x8*)(&sK[(nt * 16 + l15) * 256 + ((kb ^ swq) << 3)]);
        sacc[nt] = __builtin_amdgcn_mfma_f32_16x16x32_bf16(a8, b8, sacc[nt], 0, 0, 0);
      }
    }

    // softmax over n=64
    #pragma unroll
    for (int r = 0; r < 4; ++r) {
      const int fcl = wid * 16 + q4 * 4 + r;
      float v[4];
      #pragma unroll
      for (int nt = 0; nt < 4; ++nt)
        v[nt] = sacc[nt][r] * ss + b2f(sB[(nt * 16 + l15) * 72 + fcl]) * ps;
      float mx = fmaxf(fmaxf(v[0], v[1]), fmaxf(v[2], v[3]));
      #pragma unroll
      for (int d = 1; d < 16; d <<= 1) mx = fmaxf(mx, __shfl_xor(mx, d));
      float e[4], sum = 0.f;
      #pragma unroll
      for (int nt = 0; nt < 4; ++nt) { e[nt] = __expf(v[nt] - mx); sum += e[nt]; }
      #pragma unroll
      for (int d = 1; d < 16; d <<= 1) sum += __shfl_xor(sum, d);
      float inv = 1.0f / sum;
      #pragma unroll
      for (int nt = 0; nt < 4; ++nt)
        sW[fcl * 72 + nt * 16 + l15] = f2b(e[nt] * inv);
    }
    __syncthreads();

    // PV: wave wid owns c rows [wid*64, wid*64+64)
    f32x4 pacc[4][4];
    #pragma unroll
    for (int mf = 0; mf < 4; ++mf)
      #pragma unroll
      for (int nf = 0; nf < 4; ++nf) pacc[mf][nf] = zf;
    #pragma unroll
    for (int kt = 0; kt < 2; ++kt) {
      int k0 = kt * 32 + q4 * 8;
      bf16x8 a8[4], b8[4];
      #pragma unroll
      for (int mf = 0; mf < 4; ++mf)
        a8[mf] = *(const bf16x8*)(&sV[(wid * 64 + mf * 16 + l15) * 72 + k0]);
      #pragma unroll
      for (int nf = 0; nf < 4; ++nf)
        b8[nf] = *(const bf16x8*)(&sW[(nf * 16 + l15) * 72 + k0]);
      #pragma unroll
      for (int mf = 0; mf < 4; ++mf)
        #pragma unroll
        for (int nf = 0; nf < 4; ++nf)
          pacc[mf][nf] = __builtin_amdgcn_mfma_f32_16x16x32_bf16(a8[mf], b8[nf], pacc[mf][nf], 0, 0, 0);
    }
    // O write, transposed [f][c], 8B per store
    #pragma unroll
    for (int mf = 0; mf < 4; ++mf) {
      int cb = wid * 64 + mf * 16 + q4 * 4;
      #pragma unroll
      for (int nf = 0; nf < 4; ++nf) {
        int f = f0 + nf * 16 + l15;
        bf16x4 pk;
        #pragma unroll
        for (int r = 0; r < 4; ++r) pk[r] = (short)f2b(pacc[mf][nf][r]);
        *(bf16x4*)(Ot + (size_t)f * C_ + cb) = pk;
      }
    }
    __syncthreads();
  }
}

// -------------------------------------------------------------------------
extern "C" void kernel_launch(void* const* d_in, const int* in_sizes, int n_in,
                              void* d_out, int out_size, void* d_ws, size_t ws_size,
                              hipStream_t stream)
{
  (void)in_sizes; (void)n_in; (void)out_size;
  const float* latent     = (const float*)d_in[0];
  const float* side       = (const float*)d_in[1];
  const float* basis      = (const float*)d_in[2];
  const float* lp_norm_w  = (const float*)d_in[3];
  const float* lp_w       = (const float*)d_in[4];
  const float* lp_b       = (const float*)d_in[5];
  const float* qn_w       = (const float*)d_in[6];
  const float* qmlp_in_w  = (const float*)d_in[7];
  const float* qmlp_in_b  = (const float*)d_in[8];
  const float* qmlp_out_w = (const float*)d_in[9];
  const float* qmlp_out_b = (const float*)d_in[10];
  const float* q_w        = (const float*)d_in[11];
  const float* q_b        = (const float*)d_in[12];
  const float* k_w        = (const float*)d_in[13];
  const float* k_b        = (const float*)d_in[14];
  const float* v_w        = (const float*)d_in[15];
  const float* v_b        = (const float*)d_in[16];
  const float* o_w        = (const float*)d_in[17];
  const float* o_b        = (const float*)d_in[18];
  const float* ffn_norm_w = (const float*)d_in[19];
  const float* ffn_in_w   = (const float*)d_in[20];
  const float* ffn_in_b   = (const float*)d_in[21];
  const float* ffn_out_w  = (const float*)d_in[22];
  const float* ffn_out_b  = (const float*)d_in[23];
  const float* sc_scale   = (const float*)d_in[24];
  const float* pr_scale   = (const float*)d_in[25];
  const float* qk_scale   = (const float*)d_in[26];
  float* out = (float*)d_out;

  // ---- workspace carve, chunk count chosen to FIT ws_size ----
  // fixed: 5x(C*C bf16) + 3x(2C*C bf16) + 2x(C fp32) + 3x(B*C*PLAT bf16)
  auto align256 = [](size_t b) { return (b + 255) & ~(size_t)255; };
  const size_t fixed_bytes =
      5 * align256((size_t)C_ * C_ * 2) +
      3 * align256((size_t)2 * C_ * C_ * 2) +
      2 * align256((size_t)C_ * 4) +
      3 * align256((size_t)B_ * C_ * PLAT_ * 2);
  int nc = 16;
  for (int c = 1; c <= 16; c <<= 1) {
    size_t Pcb = (size_t)PSIDE_ / c;
    size_t need = fixed_bytes + 2 * align256((size_t)B_ * C_ * Pcb * 2)
                + align256((size_t)B_ * Pcb * 4);
    if (need <= ws_size) { nc = c; break; }
  }
  const int Pc  = PSIDE_ / nc;
  const int Tc  = T_ / nc;
  int ltc = 0; while ((1 << ltc) < Tc) ++ltc;   // log2(Tc)

  char* ws = (char*)d_ws;
  size_t off = 0;
  auto carve = [&](size_t bytes) -> char* {
    char* p = ws + off;
    off += (bytes + 255) & ~(size_t)255;
    return p;
  };
  unsigned short* wlp      = (unsigned short*)carve((size_t)C_ * C_ * 2);
  unsigned short* wqin     = (unsigned short*)carve((size_t)2 * C_ * C_ * 2);
  unsigned short* wffin    = (unsigned short*)carve((size_t)2 * C_ * C_ * 2);
  unsigned short* wk       = (unsigned short*)carve((size_t)C_ * C_ * 2);
  unsigned short* wv       = (unsigned short*)carve((size_t)C_ * C_ * 2);
  unsigned short* wfo      = (unsigned short*)carve((size_t)C_ * C_ * 2);
  unsigned short* wqeff    = (unsigned short*)carve((size_t)C_ * C_ * 2);
  unsigned short* wocat    = (unsigned short*)carve((size_t)2 * C_ * C_ * 2);  // [o_w ; qss*qmlp_out_w]
  float*          beff     = (float*)carve((size_t)C_ * 4);
  float*          bcomb    = (float*)carve((size_t)C_ * 4);
  unsigned short* latent_h = (unsigned short*)carve((size_t)B_ * C_ * PLAT_ * 2);
  unsigned short* kbuf     = (unsigned short*)carve((size_t)B_ * C_ * PLAT_ * 2);
  unsigned short* vbuf     = (unsigned short*)carve((size_t)B_ * C_ * PLAT_ * 2);
  unsigned short* big0     = (unsigned short*)carve((size_t)B_ * C_ * Pc * 2);
  unsigned short* qbuf     = (unsigned short*)carve((size_t)B_ * C_ * Pc * 2);
  float*          pscale   = (float*)carve((size_t)B_ * Pc * 4);

  const dim3 blk(256);
  const dim3 gLatA(PLAT_ / 64, 1, B_);
  const dim3 gChA(Pc / 64, 1, B_);
  const dim3 gChB(Pc / 64 * 2, 1, B_);   // CFG1: paired W-halves, adjacent dispatch
  const int NW = C_ * C_;   // 65536

  // weight prep
  wprep_k<<<dim3(NW / 256), blk, 0, stream>>>(lp_w, lp_norm_w, wlp, NW);
  wprep_k<<<dim3(2 * NW / 256), blk, 0, stream>>>(qmlp_in_w, qn_w, wqin, 2 * NW);
  wprep_k<<<dim3(2 * NW / 256), blk, 0, stream>>>(ffn_in_w, ffn_norm_w, wffin, 2 * NW);
  cvt_k<<<dim3(NW / 256), blk, 0, stream>>>(k_w, wk, NW);
  cvt_k<<<dim3(NW / 256), blk, 0, stream>>>(v_w, wv, NW);
  cvt_k<<<dim3(NW / 256), blk, 0, stream>>>(ffn_out_w, wfo, NW);
  foldw_k<<<dim3(C_), blk, 0, stream>>>(q_w, qmlp_out_w, wqeff);
  foldb_k<<<dim3(1), blk, 0, stream>>>(q_w, qmlp_out_b, q_b, beff);
  cvt_k<<<dim3(NW / 256), blk, 0, stream>>>(o_w, wocat, NW);
  wscale_k<<<dim3(NW / 256), blk, 0, stream>>>(qmlp_out_w, qk_scale, wocat + (size_t)NW, NW);
  bcomb_k<<<dim3(1), blk, 0, stream>>>(o_b, qmlp_out_b, qk_scale, bcomb);

  // latent path (once): rms fused into lp-gemm
  gemm_k<EPI_SILU, true, false, unsigned short, true, 0, false><<<gLatA, blk, 0, stream>>>(
      latent, nullptr, wlp, lp_b, latent_h, nullptr, nullptr, PLAT_, 0, PLAT_, 0, 0);
  gemm_k<EPI_NONE, false, true, unsigned short, true, 0, false><<<gLatA, blk, 0, stream>>>(
      latent_h, nullptr, wk, k_b, kbuf, nullptr, nullptr, PLAT_, 0, PLAT_, 0, 0);
  gemm_k<EPI_NONE, false, true, unsigned short, false, 0, false><<<gLatA, blk, 0, stream>>>(
      latent_h, nullptr, wv, v_b, vbuf, nullptr, nullptr, PLAT_, 0, PLAT_, 0, 0);

  // side path, chunked over t
  for (int ch = 0; ch < nc; ++ch) {
    const int co = ch * Pc;
    const int t0 = ch * Tc;
    // big0 = swiglu_inner(qmlp_in @ rms(side))   [rms fused]
    gemm_k<EPI_SWIGLU, true, false, unsigned short, true, 1, false><<<gChB, blk, 0, stream>>>(
        side, nullptr, wqin, qmlp_in_b, big0, nullptr, nullptr, PSIDE_, co, Pc, 0, 0);
    // qbuf = (q_w @ qmlp_out) @ big0 + folded bias
    gemm_k<EPI_NONE, false, true, unsigned short, true, 0, false><<<gChA, blk, 0, stream>>>(
        big0, nullptr, wqeff, beff, qbuf, nullptr, nullptr, Pc, 0, Pc, 0, 0);
    // attention in-place over qbuf
    attn_k<<<dim3(B_ * Tc), blk, 0, stream>>>(qbuf, kbuf, vbuf, basis, sc_scale, pr_scale,
                                              qbuf, Pc, t0, ltc);
    // hidden = o_w @ attended + qss*(qmlp_out @ big0) + comb_bias
    //   -> qbuf (bf16T, in-place, UNNORMED) + pscale (per-pixel rms scale)
    gemm_k<EPI_DUALX, false, true, unsigned short, true, 0, false><<<gChA, blk, 0, stream>>>(
        qbuf, big0, wocat, bcomb, qbuf, nullptr, pscale, Pc, 0, Pc, 0, Pc);
    // FFN in: reads unnormed hiddenT, applies norm as column scale (CSIN)
    gemm_k<EPI_SWIGLU, false, true, unsigned short, true, 1, true><<<gChB, blk, 0, stream>>>(
        qbuf, nullptr, wffin, ffn_in_b, big0, nullptr, pscale, Pc, 0, Pc, 0, Pc);
    // out = wfo @ big0 + ffn_out_b + hiddenT  (single fp32 write, no RMW)
    gemm_k<EPI_RESID, false, true, float, false, 0, false><<<gChA, blk, 0, stream>>>(
        big0, nullptr, wfo, ffn_out_b, out, qbuf, nullptr, Pc, 0, PSIDE_, co, Pc);
  }
}